// Round 1
// baseline (1294.115 us; speedup 1.0000x reference)
//
#include <hip/hip_runtime.h>

#define Bn 64
#define Sn 512
#define EB 768
#define Hn 64
#define G3 192
#define Tn 16
#define Pn 32

__device__ __forceinline__ float sigmoidf_(float x) { return 1.f / (1.f + __expf(-x)); }
__device__ __forceinline__ float tanhf_(float x) { return 1.f - 2.f / (__expf(2.f * x) + 1.f); }

// ---------------- K1: xp = bert @ Wih^T + bih, both directions (z-dim) -------
// C layout: (B*S, 192). A: (32768, 768) row-major. W: (192, 768) row-major.
__global__ __launch_bounds__(256) void gemm_xp(const float* __restrict__ A,
                                               const float* __restrict__ Wf,
                                               const float* __restrict__ bf,
                                               const float* __restrict__ Wb,
                                               const float* __restrict__ bb,
                                               float* __restrict__ Cf,
                                               float* __restrict__ Cb) {
  __shared__ __align__(16) float As[16][68];
  __shared__ __align__(16) float Bs[16][68];
  const float* W = (blockIdx.z == 0) ? Wf : Wb;
  const float* bias = (blockIdx.z == 0) ? bf : bb;
  float* C = (blockIdx.z == 0) ? Cf : Cb;
  const int tid = threadIdx.x;
  const int row0 = blockIdx.x * 64;
  const int col0 = blockIdx.y * 64;
  const int r = tid >> 2;            // 0..63
  const int cq = (tid & 3) << 2;     // 0,4,8,12
  const int tx = tid & 15, ty = tid >> 4;
  float acc[4][4] = {};
  for (int k0 = 0; k0 < EB; k0 += 16) {
    float4 av = *(const float4*)&A[(size_t)(row0 + r) * EB + k0 + cq];
    float4 bv = *(const float4*)&W[(size_t)(col0 + r) * EB + k0 + cq];
    __syncthreads();
    As[cq + 0][r] = av.x; As[cq + 1][r] = av.y; As[cq + 2][r] = av.z; As[cq + 3][r] = av.w;
    Bs[cq + 0][r] = bv.x; Bs[cq + 1][r] = bv.y; Bs[cq + 2][r] = bv.z; Bs[cq + 3][r] = bv.w;
    __syncthreads();
#pragma unroll
    for (int k = 0; k < 16; ++k) {
      float4 a4 = *(const float4*)&As[k][ty * 4];
      float4 b4 = *(const float4*)&Bs[k][tx * 4];
      float aa[4] = {a4.x, a4.y, a4.z, a4.w};
      float bb2[4] = {b4.x, b4.y, b4.z, b4.w};
#pragma unroll
      for (int i = 0; i < 4; ++i)
#pragma unroll
        for (int j = 0; j < 4; ++j) acc[i][j] += aa[i] * bb2[j];
    }
  }
#pragma unroll
  for (int i = 0; i < 4; ++i) {
    int row = row0 + ty * 4 + i;
    int col = col0 + tx * 4;
    float4 o;
    o.x = acc[i][0] + bias[col + 0];
    o.y = acc[i][1] + bias[col + 1];
    o.z = acc[i][2] + bias[col + 2];
    o.w = acc[i][3] + bias[col + 3];
    *(float4*)&C[(size_t)row * G3 + col] = o;
  }
}

// ---------------- K2: Bi-GRU, one wave per (batch, direction) ---------------
__global__ __launch_bounds__(64) void gru_kernel(const float* __restrict__ xpf,
                                                 const float* __restrict__ xpb,
                                                 const float* __restrict__ Whh_f,
                                                 const float* __restrict__ bhh_f,
                                                 const float* __restrict__ Whh_b,
                                                 const float* __restrict__ bhh_b,
                                                 float* __restrict__ out) {
  __shared__ __align__(16) float Wst[3 * 16 * 64 * 4];  // [gate][kchunk][lane][4]
  __shared__ __align__(16) float hbuf[64];
  const int wg = blockIdx.x;
  const int rev = (wg >= Bn) ? 1 : 0;
  const int b = wg & (Bn - 1);
  const int l = threadIdx.x;
  const float* xp = rev ? xpb : xpf;
  const float* Whh = rev ? Whh_b : Whh_f;
  const float* bhh = rev ? bhh_b : bhh_f;
  const int dirOff = rev ? Hn : 0;
#pragma unroll
  for (int g = 0; g < 3; ++g)
#pragma unroll
    for (int c = 0; c < 16; ++c) {
      float4 w = *(const float4*)&Whh[(size_t)(g * 64 + l) * 64 + c * 4];
      *(float4*)&Wst[((g * 16 + c) * 64 + l) * 4] = w;
    }
  const float br = bhh[l], bz = bhh[64 + l], bn = bhh[128 + l];
  __syncthreads();
  float h = 0.f;
  int tt = rev ? (Sn - 1) : 0;
  const float* xp0 = xp + (size_t)(b * Sn + tt) * G3;
  float xr = xp0[l], xz = xp0[64 + l], xn = xp0[128 + l];
  for (int t = 0; t < Sn; ++t) {
    hbuf[l] = h;  // single wave: DS ops are in program order, no barrier needed
    float nxr = 0.f, nxz = 0.f, nxn = 0.f;
    if (t + 1 < Sn) {
      int tn = rev ? (Sn - 2 - t) : (t + 1);
      const float* xq = xp + (size_t)(b * Sn + tn) * G3;
      nxr = xq[l]; nxz = xq[64 + l]; nxn = xq[128 + l];
    }
    float ar = br, az = bz, an = bn;
#pragma unroll
    for (int c = 0; c < 16; ++c) {
      float4 hk = *(const float4*)&hbuf[c * 4];
      float4 wr = *(const float4*)&Wst[((0 * 16 + c) * 64 + l) * 4];
      float4 wz = *(const float4*)&Wst[((1 * 16 + c) * 64 + l) * 4];
      float4 wn = *(const float4*)&Wst[((2 * 16 + c) * 64 + l) * 4];
      ar += wr.x * hk.x + wr.y * hk.y + wr.z * hk.z + wr.w * hk.w;
      az += wz.x * hk.x + wz.y * hk.y + wz.z * hk.z + wz.w * hk.w;
      an += wn.x * hk.x + wn.y * hk.y + wn.z * hk.z + wn.w * hk.w;
    }
    float rg = sigmoidf_(xr + ar);
    float zg = sigmoidf_(xz + az);
    float ng = tanhf_(xn + rg * an);
    h = (1.f - zg) * ng + zg * h;
    out[(size_t)(b * Sn + tt) * (2 * Hn) + dirOff + l] = h;
    tt = rev ? (tt - 1) : (tt + 1);
    xr = nxr; xz = nxz; xn = nxn;
  }
}

// ---------------- K3: qkv projection -----------------------------------------
__global__ __launch_bounds__(256) void qkv_kernel(const float* __restrict__ in2,
                                                  const float* __restrict__ Wqkv,
                                                  const float* __restrict__ bqkv,
                                                  float* __restrict__ qb,
                                                  float* __restrict__ kb,
                                                  float* __restrict__ vb) {
  __shared__ float Ws[96 * 32];
  __shared__ float bs[96];
  const int tid = threadIdx.x;
  for (int i = tid; i < 96 * 32; i += 256) Ws[i] = Wqkv[i];
  if (tid < 96) bs[tid] = bqkv[tid];
  __syncthreads();
  const int idx = blockIdx.x * 256 + tid;  // b*512 + s
  float x[32];
#pragma unroll
  for (int d4 = 0; d4 < 8; ++d4) {
    float4 v = *(const float4*)&in2[(size_t)idx * 32 + d4 * 4];
    x[d4 * 4 + 0] = v.x; x[d4 * 4 + 1] = v.y; x[d4 * 4 + 2] = v.z; x[d4 * 4 + 3] = v.w;
  }
  for (int g = 0; g < 96; ++g) {
    float a = bs[g];
#pragma unroll
    for (int d = 0; d < 32; ++d) a += x[d] * Ws[g * 32 + d];
    float* dst = (g < 32) ? qb : ((g < 64) ? kb : vb);
    dst[(size_t)idx * 32 + (g & 31)] = a;
  }
}

// ---------------- K4: fused single-head attention + out_proj -----------------
__global__ __launch_bounds__(256) void attn_kernel(const float* __restrict__ qb,
                                                   const float* __restrict__ kb,
                                                   const float* __restrict__ vb,
                                                   const float* __restrict__ Wout,
                                                   const float* __restrict__ bout,
                                                   float* __restrict__ attn) {
  __shared__ float Ws[32 * 32];
  __shared__ float bs[32];
  const int tid = threadIdx.x;
  for (int i = tid; i < 1024; i += 256) Ws[i] = Wout[i];
  if (tid < 32) bs[tid] = bout[tid];
  __syncthreads();
  const int idx = blockIdx.x * 256 + tid;
  const int b = idx >> 9;
  float q[32];
#pragma unroll
  for (int d4 = 0; d4 < 8; ++d4) {
    float4 v = *(const float4*)&qb[(size_t)idx * 32 + d4 * 4];
    q[d4 * 4 + 0] = v.x; q[d4 * 4 + 1] = v.y; q[d4 * 4 + 2] = v.z; q[d4 * 4 + 3] = v.w;
  }
  const float scale = 0.17677669529663687f;  // 1/sqrt(32)
  float m = -1e30f, lsum = 0.f;
  float acc[32] = {};
  for (int kk = 0; kk < Sn; ++kk) {
    const float4* kr = (const float4*)&kb[(size_t)(b * Sn + kk) * 32];
    float s = 0.f;
#pragma unroll
    for (int d4 = 0; d4 < 8; ++d4) {
      float4 kv = kr[d4];
      s += q[d4 * 4 + 0] * kv.x + q[d4 * 4 + 1] * kv.y + q[d4 * 4 + 2] * kv.z + q[d4 * 4 + 3] * kv.w;
    }
    s *= scale;
    float mn = fmaxf(m, s);
    float e1 = __expf(m - mn);
    float p = __expf(s - mn);
    lsum = lsum * e1 + p;
    const float4* vr = (const float4*)&vb[(size_t)(b * Sn + kk) * 32];
#pragma unroll
    for (int d4 = 0; d4 < 8; ++d4) {
      float4 vv = vr[d4];
      acc[d4 * 4 + 0] = acc[d4 * 4 + 0] * e1 + p * vv.x;
      acc[d4 * 4 + 1] = acc[d4 * 4 + 1] * e1 + p * vv.y;
      acc[d4 * 4 + 2] = acc[d4 * 4 + 2] * e1 + p * vv.z;
      acc[d4 * 4 + 3] = acc[d4 * 4 + 3] * e1 + p * vv.w;
    }
    m = mn;
  }
  const float inv = 1.f / lsum;
  float a[32];
#pragma unroll
  for (int d = 0; d < 32; ++d) a[d] = acc[d] * inv;
#pragma unroll
  for (int j = 0; j < 32; ++j) {
    float o = bs[j];
#pragma unroll
    for (int d = 0; d < 32; ++d) o += a[d] * Ws[j * 32 + d];
    attn[(size_t)idx * 32 + j] = o;
  }
}

// ---------------- K5: Wcomb = Wdense(128x16) @ Wfuse_top(16x16) --------------
__global__ __launch_bounds__(256) void wcomb_kernel(const float* __restrict__ Wdense,
                                                    const float* __restrict__ Wfuse,
                                                    float* __restrict__ wcomb) {
  int e = blockIdx.x * 256 + threadIdx.x;  // grid 8 -> 2048
  int i = e >> 4, j = e & 15;
  float a = 0.f;
#pragma unroll
  for (int c = 0; c < 16; ++c) a += Wdense[i * 16 + c] * Wfuse[c * 16 + j];
  wcomb[e] = a;
}

// ---------------- K6: emissions ----------------------------------------------
__global__ __launch_bounds__(256) void emis_kernel(const float* __restrict__ lstm,
                                                   const float* __restrict__ attn,
                                                   const float* __restrict__ wcomb,
                                                   const float* __restrict__ Wfuse,
                                                   float* __restrict__ emis) {
  __shared__ float Wc[128 * 16];
  __shared__ float Wf2[32 * 16];
  const int tid = threadIdx.x;
  for (int i = tid; i < 2048; i += 256) Wc[i] = wcomb[i];
  for (int i = tid; i < 512; i += 256) Wf2[i] = Wfuse[16 * 16 + i];
  __syncthreads();
  const int idx = blockIdx.x * 256 + tid;
  float acc[16] = {};
  for (int i = 0; i < 128; i += 4) {
    float4 lv = *(const float4*)&lstm[(size_t)idx * 128 + i];
    float ll[4] = {lv.x, lv.y, lv.z, lv.w};
#pragma unroll
    for (int u = 0; u < 4; ++u)
#pragma unroll
      for (int j = 0; j < 16; ++j) acc[j] += ll[u] * Wc[(i + u) * 16 + j];
  }
  for (int d = 0; d < 32; d += 4) {
    float4 av = *(const float4*)&attn[(size_t)idx * 32 + d];
    float aa[4] = {av.x, av.y, av.z, av.w};
#pragma unroll
    for (int u = 0; u < 4; ++u)
#pragma unroll
      for (int j = 0; j < 16; ++j) acc[j] += aa[u] * Wf2[(d + u) * 16 + j];
  }
#pragma unroll
  for (int j = 0; j < 16; j += 4) {
    float4 o = {acc[j], acc[j + 1], acc[j + 2], acc[j + 3]};
    *(float4*)&emis[(size_t)idx * 16 + j] = o;
  }
}

// ---------------- K7: CRF numerator ------------------------------------------
__global__ __launch_bounds__(64) void numer_kernel(const float* __restrict__ emis,
                                                   const int* __restrict__ tgt,
                                                   const float* __restrict__ cstart,
                                                   const float* __restrict__ cend,
                                                   const float* __restrict__ ctrans,
                                                   float* __restrict__ numer) {
  const int b = blockIdx.x, l = threadIdx.x;
  float ssum = 0.f;
  for (int t = l; t < Sn; t += 64) {
    int tg = tgt[b * Sn + t];
    ssum += emis[(size_t)(b * Sn + t) * Tn + tg];
    if (t + 1 < Sn) {
      int tg2 = tgt[b * Sn + t + 1];
      ssum += ctrans[tg * Tn + tg2];
    }
  }
  if (l == 0) ssum += cstart[tgt[b * Sn]] + cend[tgt[b * Sn + Sn - 1]];
  for (int off = 32; off > 0; off >>= 1) ssum += __shfl_down(ssum, off);
  if (l == 0) numer[b] = ssum;
}

// ---------------- K8: CRF forward (denominator) ------------------------------
__global__ __launch_bounds__(64) void denom_kernel(const float* __restrict__ emis,
                                                   const float* __restrict__ cstart,
                                                   const float* __restrict__ cend,
                                                   const float* __restrict__ ctrans,
                                                   float* __restrict__ denom) {
  __shared__ float sc[16];
  __shared__ float fin[16];
  const int b = blockIdx.x;
  const int j = threadIdx.x & 15;
  float tr[16];
#pragma unroll
  for (int i = 0; i < 16; ++i) tr[i] = ctrans[i * 16 + j];
  float s = cstart[j] + emis[(size_t)(b * Sn) * Tn + j];
  for (int t = 1; t < Sn; ++t) {
    if (threadIdx.x < 16) sc[j] = s;
    __syncthreads();
    float v[16];
    float m = -1e30f;
#pragma unroll
    for (int i = 0; i < 16; ++i) { v[i] = sc[i] + tr[i]; m = fmaxf(m, v[i]); }
    float es = 0.f;
#pragma unroll
    for (int i = 0; i < 16; ++i) es += __expf(v[i] - m);
    s = emis[(size_t)(b * Sn + t) * Tn + j] + m + __logf(es);
    __syncthreads();
  }
  if (threadIdx.x < 16) fin[j] = s + cend[j];
  __syncthreads();
  if (threadIdx.x == 0) {
    float m = -1e30f;
#pragma unroll
    for (int i = 0; i < 16; ++i) m = fmaxf(m, fin[i]);
    float es = 0.f;
#pragma unroll
    for (int i = 0; i < 16; ++i) es += __expf(fin[i] - m);
    denom[b] = m + __logf(es);
  }
}

// ---------------- K9: final scalar -------------------------------------------
__global__ __launch_bounds__(64) void final_kernel(const float* __restrict__ numer,
                                                   const float* __restrict__ denom,
                                                   float* __restrict__ out) {
  const int l = threadIdx.x;
  float d = denom[l] - numer[l];
  for (int off = 32; off > 0; off >>= 1) d += __shfl_down(d, off);
  if (l == 0) out[0] = d * (1.f / 64.f);
}

extern "C" void kernel_launch(void* const* d_in, const int* in_sizes, int n_in,
                              void* d_out, int out_size, void* d_ws, size_t ws_size,
                              hipStream_t stream) {
  (void)in_sizes; (void)n_in; (void)out_size; (void)ws_size;
  const float* bert = (const float*)d_in[0];
  const float* in2 = (const float*)d_in[1];
  const int* tgt = (const int*)d_in[2];
  const float* Wih_f = (const float*)d_in[3];
  const float* Whh_f = (const float*)d_in[4];
  const float* bih_f = (const float*)d_in[5];
  const float* bhh_f = (const float*)d_in[6];
  const float* Wih_b = (const float*)d_in[7];
  const float* Whh_b = (const float*)d_in[8];
  const float* bih_b = (const float*)d_in[9];
  const float* bhh_b = (const float*)d_in[10];
  const float* Wdense = (const float*)d_in[11];
  const float* in_proj_w = (const float*)d_in[12];
  const float* in_proj_b = (const float*)d_in[13];
  const float* out_proj_w = (const float*)d_in[14];
  const float* out_proj_b = (const float*)d_in[15];
  const float* Wfuse = (const float*)d_in[16];
  const float* cstart = (const float*)d_in[17];
  const float* cend = (const float*)d_in[18];
  const float* ctrans = (const float*)d_in[19];

  float* ws = (float*)d_ws;
  float* xpf = ws;                                  // B*S*192
  float* xpb = xpf + (size_t)Bn * Sn * G3;          // B*S*192
  float* lstm = xpb + (size_t)Bn * Sn * G3;         // B*S*128
  float* qb = lstm + (size_t)Bn * Sn * 2 * Hn;      // B*S*32
  float* kb = qb + (size_t)Bn * Sn * Pn;
  float* vb = kb + (size_t)Bn * Sn * Pn;
  float* attn = vb + (size_t)Bn * Sn * Pn;
  float* emis = attn + (size_t)Bn * Sn * Pn;        // B*S*16
  float* wcomb = emis + (size_t)Bn * Sn * Tn;       // 2048
  float* numer = wcomb + 128 * 16;                  // 64
  float* denom = numer + Bn;                        // 64

  dim3 gg(Bn * Sn / 64, 3, 2);
  gemm_xp<<<gg, 256, 0, stream>>>(bert, Wih_f, bih_f, Wih_b, bih_b, xpf, xpb);
  qkv_kernel<<<Bn * Sn / 256, 256, 0, stream>>>(in2, in_proj_w, in_proj_b, qb, kb, vb);
  wcomb_kernel<<<8, 256, 0, stream>>>(Wdense, Wfuse, wcomb);
  gru_kernel<<<2 * Bn, 64, 0, stream>>>(xpf, xpb, Whh_f, bhh_f, Whh_b, bhh_b, lstm);
  attn_kernel<<<Bn * Sn / 256, 256, 0, stream>>>(qb, kb, vb, out_proj_w, out_proj_b, attn);
  emis_kernel<<<Bn * Sn / 256, 256, 0, stream>>>(lstm, attn, wcomb, Wfuse, emis);
  numer_kernel<<<Bn, 64, 0, stream>>>(emis, tgt, cstart, cend, ctrans, numer);
  denom_kernel<<<Bn, 64, 0, stream>>>(emis, cstart, cend, ctrans, denom);
  final_kernel<<<1, 64, 0, stream>>>(numer, denom, (float*)d_out);
}

// Round 2
// 1265.951 us; speedup vs baseline: 1.0222x; 1.0222x over previous
//
#include <hip/hip_runtime.h>

#define Bn 64
#define Sn 512
#define EB 768
#define Hn 64
#define G3 192
#define Tn 16
#define Pn 32

__device__ __forceinline__ float sigmoidf_(float x) { return 1.f / (1.f + __expf(-x)); }
__device__ __forceinline__ float tanhf_(float x) { return 1.f - 2.f / (__expf(2.f * x) + 1.f); }

__device__ __forceinline__ unsigned short f2bf(float x) {
  union { float f; unsigned u; } v; v.f = x;
  unsigned r = v.u + 0x7fff + ((v.u >> 16) & 1);  // RNE
  return (unsigned short)(r >> 16);
}

typedef __attribute__((ext_vector_type(8))) short short8;
typedef __attribute__((ext_vector_type(4))) float f32x4;

// ---------------- K1: C(32768x384) = bert(32768x768) @ [Wf;Wb]^T + bias, bf16 MFMA
__global__ __launch_bounds__(256) void gemm_mfma(const float* __restrict__ A,
                                                 const float* __restrict__ Wf,
                                                 const float* __restrict__ Wb,
                                                 const float* __restrict__ bf,
                                                 const float* __restrict__ bb,
                                                 float* __restrict__ C) {
  __shared__ __align__(16) unsigned short As[128 * 40];  // pad 32->40 (2-way max)
  __shared__ __align__(16) unsigned short Bs[128 * 40];
  const int tid = threadIdx.x;
  const int n0 = blockIdx.x * 128;  // N-tile fast -> A rows reused across adjacent blocks
  const int m0 = blockIdx.y * 128;
  const int wv = tid >> 6;
  const int lane = tid & 63;
  const int wm = (wv >> 1) * 64, wn = (wv & 1) * 64;
  const int fr = lane & 15, fq = lane >> 4;
  const int srow = tid >> 1;           // 0..127
  const int shalf = (tid & 1) * 16;    // 0 or 16 (k offset)
  const int bcol = n0 + srow;          // 0..383
  const float* Wrow = (bcol < G3) ? (Wf + (size_t)bcol * EB) : (Wb + (size_t)(bcol - G3) * EB);
  const float* Arow = A + (size_t)(m0 + srow) * EB;
  f32x4 acc[4][4];
#pragma unroll
  for (int i = 0; i < 4; ++i)
#pragma unroll
    for (int j = 0; j < 4; ++j) acc[i][j] = (f32x4){0.f, 0.f, 0.f, 0.f};

  for (int k0 = 0; k0 < EB; k0 += 32) {
    float4 a0 = *(const float4*)&Arow[k0 + shalf + 0];
    float4 a1 = *(const float4*)&Arow[k0 + shalf + 4];
    float4 a2 = *(const float4*)&Arow[k0 + shalf + 8];
    float4 a3 = *(const float4*)&Arow[k0 + shalf + 12];
    float4 b0 = *(const float4*)&Wrow[k0 + shalf + 0];
    float4 b1 = *(const float4*)&Wrow[k0 + shalf + 4];
    float4 b2 = *(const float4*)&Wrow[k0 + shalf + 8];
    float4 b3 = *(const float4*)&Wrow[k0 + shalf + 12];
    __syncthreads();
    short8 pa, pb;
    pa[0] = f2bf(a0.x); pa[1] = f2bf(a0.y); pa[2] = f2bf(a0.z); pa[3] = f2bf(a0.w);
    pa[4] = f2bf(a1.x); pa[5] = f2bf(a1.y); pa[6] = f2bf(a1.z); pa[7] = f2bf(a1.w);
    *(short8*)&As[srow * 40 + shalf] = pa;
    pa[0] = f2bf(a2.x); pa[1] = f2bf(a2.y); pa[2] = f2bf(a2.z); pa[3] = f2bf(a2.w);
    pa[4] = f2bf(a3.x); pa[5] = f2bf(a3.y); pa[6] = f2bf(a3.z); pa[7] = f2bf(a3.w);
    *(short8*)&As[srow * 40 + shalf + 8] = pa;
    pb[0] = f2bf(b0.x); pb[1] = f2bf(b0.y); pb[2] = f2bf(b0.z); pb[3] = f2bf(b0.w);
    pb[4] = f2bf(b1.x); pb[5] = f2bf(b1.y); pb[6] = f2bf(b1.z); pb[7] = f2bf(b1.w);
    *(short8*)&Bs[srow * 40 + shalf] = pb;
    pb[0] = f2bf(b2.x); pb[1] = f2bf(b2.y); pb[2] = f2bf(b2.z); pb[3] = f2bf(b2.w);
    pb[4] = f2bf(b3.x); pb[5] = f2bf(b3.y); pb[6] = f2bf(b3.z); pb[7] = f2bf(b3.w);
    *(short8*)&Bs[srow * 40 + shalf + 8] = pb;
    __syncthreads();
    short8 af[4], bfv[4];
#pragma unroll
    for (int i = 0; i < 4; ++i) af[i] = *(short8*)&As[(wm + i * 16 + fr) * 40 + fq * 8];
#pragma unroll
    for (int j = 0; j < 4; ++j) bfv[j] = *(short8*)&Bs[(wn + j * 16 + fr) * 40 + fq * 8];
#pragma unroll
    for (int i = 0; i < 4; ++i)
#pragma unroll
      for (int j = 0; j < 4; ++j)
        acc[i][j] = __builtin_amdgcn_mfma_f32_16x16x32_bf16(af[i], bfv[j], acc[i][j], 0, 0, 0);
  }
  // epilogue: D[row=fq*4+reg][col=fr] per 16x16 tile, + bias
#pragma unroll
  for (int j = 0; j < 4; ++j) {
    int col = n0 + wn + j * 16 + fr;
    float bias = (col < G3) ? bf[col] : bb[col - G3];
#pragma unroll
    for (int i = 0; i < 4; ++i) {
      int rowb = m0 + wm + i * 16 + fq * 4;
#pragma unroll
      for (int rg = 0; rg < 4; ++rg)
        C[(size_t)(rowb + rg) * 384 + col] = acc[i][j][rg] + bias;
    }
  }
}

// ---------------- K2: Bi-GRU, one wave per (batch,dir), Whh in registers -----
__global__ __launch_bounds__(64, 1) void gru_kernel(const float* __restrict__ C,
                                                    const float* __restrict__ Whh_f,
                                                    const float* __restrict__ bhh_f,
                                                    const float* __restrict__ Whh_b,
                                                    const float* __restrict__ bhh_b,
                                                    float* __restrict__ out) {
  __shared__ __align__(16) float hbuf[64];
  const int wg = blockIdx.x;
  const int rev = (wg >= Bn) ? 1 : 0;
  const int b = wg & (Bn - 1);
  const int l = threadIdx.x;
  const float* Whh = rev ? Whh_b : Whh_f;
  const float* bhh = rev ? bhh_b : bhh_f;
  const int colBase = rev ? G3 : 0;
  const int dirOff = rev ? Hn : 0;
  // lane l holds rows l, 64+l, 128+l of Whh: 192 VGPRs
  float2 wr[32], wz[32], wn[32];
#pragma unroll
  for (int k2 = 0; k2 < 32; ++k2) {
    wr[k2] = *(const float2*)&Whh[(size_t)(0 * 64 + l) * 64 + 2 * k2];
    wz[k2] = *(const float2*)&Whh[(size_t)(1 * 64 + l) * 64 + 2 * k2];
    wn[k2] = *(const float2*)&Whh[(size_t)(2 * 64 + l) * 64 + 2 * k2];
  }
  const float br = bhh[l], bz = bhh[64 + l], bn = bhh[128 + l];
  float h = 0.f;
  int tt = rev ? (Sn - 1) : 0;
  const int stp = rev ? -1 : 1;
  const float* xrow = C + (size_t)(b * Sn + tt) * 384 + colBase;
  float xr = xrow[l], xz = xrow[64 + l], xn = xrow[128 + l];
  for (int t = 0; t < Sn; ++t) {
    hbuf[l] = h;  // single wave: DS ops in program order
    float nxr = 0.f, nxz = 0.f, nxn = 0.f;
    if (t + 1 < Sn) {
      const float* xq = C + (size_t)(b * Sn + tt + stp) * 384 + colBase;
      nxr = xq[l]; nxz = xq[64 + l]; nxn = xq[128 + l];
    }
    float ar0 = 0.f, ar1 = 0.f, az0 = 0.f, az1 = 0.f, an0 = 0.f, an1 = 0.f;
    float ar2 = 0.f, ar3 = 0.f, az2 = 0.f, az3 = 0.f, an2 = 0.f, an3 = 0.f;
#pragma unroll
    for (int k4 = 0; k4 < 16; ++k4) {
      float4 h4 = *(const float4*)&hbuf[k4 * 4];  // same-address broadcast
      float2 w;
      w = wr[2 * k4];     ar0 += w.x * h4.x; ar1 += w.y * h4.y;
      w = wr[2 * k4 + 1]; ar2 += w.x * h4.z; ar3 += w.y * h4.w;
      w = wz[2 * k4];     az0 += w.x * h4.x; az1 += w.y * h4.y;
      w = wz[2 * k4 + 1]; az2 += w.x * h4.z; az3 += w.y * h4.w;
      w = wn[2 * k4];     an0 += w.x * h4.x; an1 += w.y * h4.y;
      w = wn[2 * k4 + 1]; an2 += w.x * h4.z; an3 += w.y * h4.w;
    }
    float ar = br + (ar0 + ar1) + (ar2 + ar3);
    float az = bz + (az0 + az1) + (az2 + az3);
    float an = bn + (an0 + an1) + (an2 + an3);
    float rg = sigmoidf_(xr + ar);
    float zg = sigmoidf_(xz + az);
    float ng = tanhf_(xn + rg * an);
    h = (1.f - zg) * ng + zg * h;
    out[(size_t)(b * Sn + tt) * (2 * Hn) + dirOff + l] = h;
    tt += stp;
    xr = nxr; xz = nxz; xn = nxn;
  }
}

// ---------------- K3: qkv projection -----------------------------------------
__global__ __launch_bounds__(256) void qkv_kernel(const float* __restrict__ in2,
                                                  const float* __restrict__ Wqkv,
                                                  const float* __restrict__ bqkv,
                                                  float* __restrict__ qb,
                                                  float* __restrict__ kb,
                                                  float* __restrict__ vb) {
  __shared__ float Ws[96 * 32];
  __shared__ float bs[96];
  const int tid = threadIdx.x;
  for (int i = tid; i < 96 * 32; i += 256) Ws[i] = Wqkv[i];
  if (tid < 96) bs[tid] = bqkv[tid];
  __syncthreads();
  const int idx = blockIdx.x * 256 + tid;
  float x[32];
#pragma unroll
  for (int d4 = 0; d4 < 8; ++d4) {
    float4 v = *(const float4*)&in2[(size_t)idx * 32 + d4 * 4];
    x[d4 * 4 + 0] = v.x; x[d4 * 4 + 1] = v.y; x[d4 * 4 + 2] = v.z; x[d4 * 4 + 3] = v.w;
  }
  for (int g = 0; g < 96; ++g) {
    float a = bs[g];
#pragma unroll
    for (int d = 0; d < 32; ++d) a += x[d] * Ws[g * 32 + d];
    float* dst = (g < 32) ? qb : ((g < 64) ? kb : vb);
    dst[(size_t)idx * 32 + (g & 31)] = a;
  }
}

// ---------------- K4: fused single-head attention + out_proj -----------------
__global__ __launch_bounds__(256) void attn_kernel(const float* __restrict__ qb,
                                                   const float* __restrict__ kb,
                                                   const float* __restrict__ vb,
                                                   const float* __restrict__ Wout,
                                                   const float* __restrict__ bout,
                                                   float* __restrict__ attn) {
  __shared__ float Ws[32 * 32];
  __shared__ float bs[32];
  const int tid = threadIdx.x;
  for (int i = tid; i < 1024; i += 256) Ws[i] = Wout[i];
  if (tid < 32) bs[tid] = bout[tid];
  __syncthreads();
  const int idx = blockIdx.x * 256 + tid;
  const int b = idx >> 9;
  float q[32];
#pragma unroll
  for (int d4 = 0; d4 < 8; ++d4) {
    float4 v = *(const float4*)&qb[(size_t)idx * 32 + d4 * 4];
    q[d4 * 4 + 0] = v.x; q[d4 * 4 + 1] = v.y; q[d4 * 4 + 2] = v.z; q[d4 * 4 + 3] = v.w;
  }
  const float scale = 0.17677669529663687f;  // 1/sqrt(32)
  float m = -1e30f, lsum = 0.f;
  float acc[32] = {};
  for (int kk = 0; kk < Sn; ++kk) {
    const float4* kr = (const float4*)&kb[(size_t)(b * Sn + kk) * 32];
    float s = 0.f;
#pragma unroll
    for (int d4 = 0; d4 < 8; ++d4) {
      float4 kv = kr[d4];
      s += q[d4 * 4 + 0] * kv.x + q[d4 * 4 + 1] * kv.y + q[d4 * 4 + 2] * kv.z + q[d4 * 4 + 3] * kv.w;
    }
    s *= scale;
    float mn = fmaxf(m, s);
    float e1 = __expf(m - mn);
    float p = __expf(s - mn);
    lsum = lsum * e1 + p;
    const float4* vr = (const float4*)&vb[(size_t)(b * Sn + kk) * 32];
#pragma unroll
    for (int d4 = 0; d4 < 8; ++d4) {
      float4 vv = vr[d4];
      acc[d4 * 4 + 0] = acc[d4 * 4 + 0] * e1 + p * vv.x;
      acc[d4 * 4 + 1] = acc[d4 * 4 + 1] * e1 + p * vv.y;
      acc[d4 * 4 + 2] = acc[d4 * 4 + 2] * e1 + p * vv.z;
      acc[d4 * 4 + 3] = acc[d4 * 4 + 3] * e1 + p * vv.w;
    }
    m = mn;
  }
  const float inv = 1.f / lsum;
  float a[32];
#pragma unroll
  for (int d = 0; d < 32; ++d) a[d] = acc[d] * inv;
#pragma unroll
  for (int j = 0; j < 32; ++j) {
    float o = bs[j];
#pragma unroll
    for (int d = 0; d < 32; ++d) o += a[d] * Ws[j * 32 + d];
    attn[(size_t)idx * 32 + j] = o;
  }
}

// ---------------- K5: Wcomb = Wdense(128x16) @ Wfuse_top(16x16) --------------
__global__ __launch_bounds__(256) void wcomb_kernel(const float* __restrict__ Wdense,
                                                    const float* __restrict__ Wfuse,
                                                    float* __restrict__ wcomb) {
  int e = blockIdx.x * 256 + threadIdx.x;
  int i = e >> 4, j = e & 15;
  float a = 0.f;
#pragma unroll
  for (int c = 0; c < 16; ++c) a += Wdense[i * 16 + c] * Wfuse[c * 16 + j];
  wcomb[e] = a;
}

// ---------------- K6: emissions ----------------------------------------------
__global__ __launch_bounds__(256) void emis_kernel(const float* __restrict__ lstm,
                                                   const float* __restrict__ attn,
                                                   const float* __restrict__ wcomb,
                                                   const float* __restrict__ Wfuse,
                                                   float* __restrict__ emis) {
  __shared__ float Wc[128 * 16];
  __shared__ float Wf2[32 * 16];
  const int tid = threadIdx.x;
  for (int i = tid; i < 2048; i += 256) Wc[i] = wcomb[i];
  for (int i = tid; i < 512; i += 256) Wf2[i] = Wfuse[16 * 16 + i];
  __syncthreads();
  const int idx = blockIdx.x * 256 + tid;
  float acc[16] = {};
  for (int i = 0; i < 128; i += 4) {
    float4 lv = *(const float4*)&lstm[(size_t)idx * 128 + i];
    float ll[4] = {lv.x, lv.y, lv.z, lv.w};
#pragma unroll
    for (int u = 0; u < 4; ++u)
#pragma unroll
      for (int j = 0; j < 16; ++j) acc[j] += ll[u] * Wc[(i + u) * 16 + j];
  }
  for (int d = 0; d < 32; d += 4) {
    float4 av = *(const float4*)&attn[(size_t)idx * 32 + d];
    float aa[4] = {av.x, av.y, av.z, av.w};
#pragma unroll
    for (int u = 0; u < 4; ++u)
#pragma unroll
      for (int j = 0; j < 16; ++j) acc[j] += aa[u] * Wf2[(d + u) * 16 + j];
  }
#pragma unroll
  for (int j = 0; j < 16; j += 4) {
    float4 o = {acc[j], acc[j + 1], acc[j + 2], acc[j + 3]};
    *(float4*)&emis[(size_t)idx * 16 + j] = o;
  }
}

// ---------------- K7: CRF numerator ------------------------------------------
__global__ __launch_bounds__(64) void numer_kernel(const float* __restrict__ emis,
                                                   const int* __restrict__ tgt,
                                                   const float* __restrict__ cstart,
                                                   const float* __restrict__ cend,
                                                   const float* __restrict__ ctrans,
                                                   float* __restrict__ numer) {
  const int b = blockIdx.x, l = threadIdx.x;
  float ssum = 0.f;
  for (int t = l; t < Sn; t += 64) {
    int tg = tgt[b * Sn + t];
    ssum += emis[(size_t)(b * Sn + t) * Tn + tg];
    if (t + 1 < Sn) {
      int tg2 = tgt[b * Sn + t + 1];
      ssum += ctrans[tg * Tn + tg2];
    }
  }
  if (l == 0) ssum += cstart[tgt[b * Sn]] + cend[tgt[b * Sn + Sn - 1]];
  for (int off = 32; off > 0; off >>= 1) ssum += __shfl_down(ssum, off);
  if (l == 0) numer[b] = ssum;
}

// ---------------- K8: CRF forward (denominator) ------------------------------
__global__ __launch_bounds__(64) void denom_kernel(const float* __restrict__ emis,
                                                   const float* __restrict__ cstart,
                                                   const float* __restrict__ cend,
                                                   const float* __restrict__ ctrans,
                                                   float* __restrict__ denom) {
  __shared__ float sc[16];
  __shared__ float fin[16];
  const int b = blockIdx.x;
  const int j = threadIdx.x & 15;
  float tr[16];
#pragma unroll
  for (int i = 0; i < 16; ++i) tr[i] = ctrans[i * 16 + j];
  float s = cstart[j] + emis[(size_t)(b * Sn) * Tn + j];
  for (int t = 1; t < Sn; ++t) {
    if (threadIdx.x < 16) sc[j] = s;
    __syncthreads();
    float v[16];
    float m = -1e30f;
#pragma unroll
    for (int i = 0; i < 16; ++i) { v[i] = sc[i] + tr[i]; m = fmaxf(m, v[i]); }
    float es = 0.f;
#pragma unroll
    for (int i = 0; i < 16; ++i) es += __expf(v[i] - m);
    s = emis[(size_t)(b * Sn + t) * Tn + j] + m + __logf(es);
    __syncthreads();
  }
  if (threadIdx.x < 16) fin[j] = s + cend[j];
  __syncthreads();
  if (threadIdx.x == 0) {
    float m = -1e30f;
#pragma unroll
    for (int i = 0; i < 16; ++i) m = fmaxf(m, fin[i]);
    float es = 0.f;
#pragma unroll
    for (int i = 0; i < 16; ++i) es += __expf(fin[i] - m);
    denom[b] = m + __logf(es);
  }
}

// ---------------- K9: final scalar -------------------------------------------
__global__ __launch_bounds__(64) void final_kernel(const float* __restrict__ numer,
                                                   const float* __restrict__ denom,
                                                   float* __restrict__ out) {
  const int l = threadIdx.x;
  float d = denom[l] - numer[l];
  for (int off = 32; off > 0; off >>= 1) d += __shfl_down(d, off);
  if (l == 0) out[0] = d * (1.f / 64.f);
}

extern "C" void kernel_launch(void* const* d_in, const int* in_sizes, int n_in,
                              void* d_out, int out_size, void* d_ws, size_t ws_size,
                              hipStream_t stream) {
  (void)in_sizes; (void)n_in; (void)out_size; (void)ws_size;
  const float* bert = (const float*)d_in[0];
  const float* in2 = (const float*)d_in[1];
  const int* tgt = (const int*)d_in[2];
  const float* Wih_f = (const float*)d_in[3];
  const float* Whh_f = (const float*)d_in[4];
  const float* bih_f = (const float*)d_in[5];
  const float* bhh_f = (const float*)d_in[6];
  const float* Wih_b = (const float*)d_in[7];
  const float* Whh_b = (const float*)d_in[8];
  const float* bih_b = (const float*)d_in[9];
  const float* bhh_b = (const float*)d_in[10];
  const float* Wdense = (const float*)d_in[11];
  const float* in_proj_w = (const float*)d_in[12];
  const float* in_proj_b = (const float*)d_in[13];
  const float* out_proj_w = (const float*)d_in[14];
  const float* out_proj_b = (const float*)d_in[15];
  const float* Wfuse = (const float*)d_in[16];
  const float* cstart = (const float*)d_in[17];
  const float* cend = (const float*)d_in[18];
  const float* ctrans = (const float*)d_in[19];

  float* ws = (float*)d_ws;
  float* C = ws;                                    // B*S*384
  float* lstm = C + (size_t)Bn * Sn * 384;          // B*S*128
  float* qb = lstm + (size_t)Bn * Sn * 2 * Hn;      // B*S*32
  float* kb = qb + (size_t)Bn * Sn * Pn;
  float* vb = kb + (size_t)Bn * Sn * Pn;
  float* attn = vb + (size_t)Bn * Sn * Pn;
  float* emis = attn + (size_t)Bn * Sn * Pn;        // B*S*16
  float* wcomb = emis + (size_t)Bn * Sn * Tn;       // 2048
  float* numer = wcomb + 128 * 16;                  // 64
  float* denom = numer + Bn;                        // 64

  dim3 gg(3, Bn * Sn / 128);  // N-tile fast: A rows reused in L2 across adjacent blocks
  gemm_mfma<<<gg, 256, 0, stream>>>(bert, Wih_f, Wih_b, bih_f, bih_b, C);
  qkv_kernel<<<Bn * Sn / 256, 256, 0, stream>>>(in2, in_proj_w, in_proj_b, qb, kb, vb);
  wcomb_kernel<<<8, 256, 0, stream>>>(Wdense, Wfuse, wcomb);
  gru_kernel<<<2 * Bn, 64, 0, stream>>>(C, Whh_f, bhh_f, Whh_b, bhh_b, lstm);
  attn_kernel<<<Bn * Sn / 256, 256, 0, stream>>>(qb, kb, vb, out_proj_w, out_proj_b, attn);
  emis_kernel<<<Bn * Sn / 256, 256, 0, stream>>>(lstm, attn, wcomb, Wfuse, emis);
  numer_kernel<<<Bn, 64, 0, stream>>>(emis, tgt, cstart, cend, ctrans, numer);
  denom_kernel<<<Bn, 64, 0, stream>>>(emis, cstart, cend, ctrans, denom);
  final_kernel<<<1, 64, 0, stream>>>(numer, denom, (float*)d_out);
}

// Round 3
// 1069.513 us; speedup vs baseline: 1.2100x; 1.1837x over previous
//
#include <hip/hip_runtime.h>

#define Bn 64
#define Sn 512
#define EB 768
#define Hn 64
#define G3 192
#define Tn 16
#define Pn 32

__device__ __forceinline__ float sigmoidf_(float x) { return 1.f / (1.f + __expf(-x)); }
__device__ __forceinline__ float tanhf_(float x) { return 1.f - 2.f / (__expf(2.f * x) + 1.f); }

__device__ __forceinline__ unsigned short f2bf(float x) {
  union { float f; unsigned u; } v; v.f = x;
  unsigned r = v.u + 0x7fff + ((v.u >> 16) & 1);  // RNE
  return (unsigned short)(r >> 16);
}

typedef __attribute__((ext_vector_type(8))) short short8;
typedef __attribute__((ext_vector_type(4))) float f32x4;

// ---------------- K1: C(32768x384) = bert(32768x768) @ [Wf;Wb]^T + bias, bf16 MFMA
__global__ __launch_bounds__(256) void gemm_mfma(const float* __restrict__ A,
                                                 const float* __restrict__ Wf,
                                                 const float* __restrict__ Wb,
                                                 const float* __restrict__ bf,
                                                 const float* __restrict__ bb,
                                                 float* __restrict__ C) {
  __shared__ __align__(16) unsigned short As[128 * 40];
  __shared__ __align__(16) unsigned short Bs[128 * 40];
  const int tid = threadIdx.x;
  const int n0 = blockIdx.x * 128;
  const int m0 = blockIdx.y * 128;
  const int wv = tid >> 6;
  const int lane = tid & 63;
  const int wm = (wv >> 1) * 64, wn = (wv & 1) * 64;
  const int fr = lane & 15, fq = lane >> 4;
  const int srow = tid >> 1;
  const int shalf = (tid & 1) * 16;
  const int bcol = n0 + srow;
  const float* Wrow = (bcol < G3) ? (Wf + (size_t)bcol * EB) : (Wb + (size_t)(bcol - G3) * EB);
  const float* Arow = A + (size_t)(m0 + srow) * EB;
  f32x4 acc[4][4];
#pragma unroll
  for (int i = 0; i < 4; ++i)
#pragma unroll
    for (int j = 0; j < 4; ++j) acc[i][j] = (f32x4){0.f, 0.f, 0.f, 0.f};

  for (int k0 = 0; k0 < EB; k0 += 32) {
    float4 a0 = *(const float4*)&Arow[k0 + shalf + 0];
    float4 a1 = *(const float4*)&Arow[k0 + shalf + 4];
    float4 a2 = *(const float4*)&Arow[k0 + shalf + 8];
    float4 a3 = *(const float4*)&Arow[k0 + shalf + 12];
    float4 b0 = *(const float4*)&Wrow[k0 + shalf + 0];
    float4 b1 = *(const float4*)&Wrow[k0 + shalf + 4];
    float4 b2 = *(const float4*)&Wrow[k0 + shalf + 8];
    float4 b3 = *(const float4*)&Wrow[k0 + shalf + 12];
    __syncthreads();
    short8 pa, pb;
    pa[0] = f2bf(a0.x); pa[1] = f2bf(a0.y); pa[2] = f2bf(a0.z); pa[3] = f2bf(a0.w);
    pa[4] = f2bf(a1.x); pa[5] = f2bf(a1.y); pa[6] = f2bf(a1.z); pa[7] = f2bf(a1.w);
    *(short8*)&As[srow * 40 + shalf] = pa;
    pa[0] = f2bf(a2.x); pa[1] = f2bf(a2.y); pa[2] = f2bf(a2.z); pa[3] = f2bf(a2.w);
    pa[4] = f2bf(a3.x); pa[5] = f2bf(a3.y); pa[6] = f2bf(a3.z); pa[7] = f2bf(a3.w);
    *(short8*)&As[srow * 40 + shalf + 8] = pa;
    pb[0] = f2bf(b0.x); pb[1] = f2bf(b0.y); pb[2] = f2bf(b0.z); pb[3] = f2bf(b0.w);
    pb[4] = f2bf(b1.x); pb[5] = f2bf(b1.y); pb[6] = f2bf(b1.z); pb[7] = f2bf(b1.w);
    *(short8*)&Bs[srow * 40 + shalf] = pb;
    pb[0] = f2bf(b2.x); pb[1] = f2bf(b2.y); pb[2] = f2bf(b2.z); pb[3] = f2bf(b2.w);
    pb[4] = f2bf(b3.x); pb[5] = f2bf(b3.y); pb[6] = f2bf(b3.z); pb[7] = f2bf(b3.w);
    *(short8*)&Bs[srow * 40 + shalf + 8] = pb;
    __syncthreads();
    short8 af[4], bfv[4];
#pragma unroll
    for (int i = 0; i < 4; ++i) af[i] = *(short8*)&As[(wm + i * 16 + fr) * 40 + fq * 8];
#pragma unroll
    for (int j = 0; j < 4; ++j) bfv[j] = *(short8*)&Bs[(wn + j * 16 + fr) * 40 + fq * 8];
#pragma unroll
    for (int i = 0; i < 4; ++i)
#pragma unroll
      for (int j = 0; j < 4; ++j)
        acc[i][j] = __builtin_amdgcn_mfma_f32_16x16x32_bf16(af[i], bfv[j], acc[i][j], 0, 0, 0);
  }
#pragma unroll
  for (int j = 0; j < 4; ++j) {
    int col = n0 + wn + j * 16 + fr;
    float bias = (col < G3) ? bf[col] : bb[col - G3];
#pragma unroll
    for (int i = 0; i < 4; ++i) {
      int rowb = m0 + wm + i * 16 + fq * 4;
#pragma unroll
      for (int rg = 0; rg < 4; ++rg)
        C[(size_t)(rowb + rg) * 384 + col] = acc[i][j][rg] + bias;
    }
  }
}

// ---------------- K2: Bi-GRU, 4 waves per (batch,dir), K-split matvec --------
// Lane l of wave w holds Whh rows {l,64+l,128+l}, cols [16w,16w+16) in regs (48 f).
// Per step: broadcast-read h chunk, 48 FMAs, LDS partial exchange, redundant
// activation on all waves.
__global__ __launch_bounds__(256, 1) void gru_kernel(const float* __restrict__ C,
                                                     const float* __restrict__ Whh_f,
                                                     const float* __restrict__ bhh_f,
                                                     const float* __restrict__ Whh_b,
                                                     const float* __restrict__ bhh_b,
                                                     float* __restrict__ out) {
  __shared__ __align__(16) float hbuf[64];
  __shared__ __align__(16) float part[3 * 4 * 64];  // [gate][wave][lane]
  const int wg = blockIdx.x;
  const int rev = (wg >= Bn) ? 1 : 0;
  const int b = wg & (Bn - 1);
  const int tid = threadIdx.x;
  const int w = tid >> 6;
  const int l = tid & 63;
  const float* Whh = rev ? Whh_b : Whh_f;
  const float* bhh = rev ? bhh_b : bhh_f;
  const int colBase = rev ? G3 : 0;
  const int dirOff = rev ? Hn : 0;
  // 12 float4 of weights per lane
  float4 wgt[3][4];
#pragma unroll
  for (int g = 0; g < 3; ++g)
#pragma unroll
    for (int q = 0; q < 4; ++q)
      wgt[g][q] = *(const float4*)&Whh[(size_t)(g * 64 + l) * 64 + 16 * w + 4 * q];
  const float br = bhh[l], bz = bhh[64 + l], bn = bhh[128 + l];
  float h = 0.f;
  if (w == 0) hbuf[l] = 0.f;
  int tt = rev ? (Sn - 1) : 0;
  const int stp = rev ? -1 : 1;
  const float* xrow = C + (size_t)(b * Sn + tt) * 384 + colBase;
  float xr = xrow[l], xz = xrow[64 + l], xn = xrow[128 + l];
  for (int t = 0; t < Sn; ++t) {
    __syncthreads();  // A: hbuf holds h_{t-1}
    float4 h0 = *(const float4*)&hbuf[16 * w + 0];
    float4 h1 = *(const float4*)&hbuf[16 * w + 4];
    float4 h2 = *(const float4*)&hbuf[16 * w + 8];
    float4 h3 = *(const float4*)&hbuf[16 * w + 12];
    // prefetch next x (latency hidden behind this step)
    float nxr = 0.f, nxz = 0.f, nxn = 0.f;
    if (t + 1 < Sn) {
      const float* xq = C + (size_t)(b * Sn + tt + stp) * 384 + colBase;
      nxr = xq[l]; nxz = xq[64 + l]; nxn = xq[128 + l];
    }
    float pg[3];
#pragma unroll
    for (int g = 0; g < 3; ++g) {
      float4 wa = wgt[g][0], wb2 = wgt[g][1], wc = wgt[g][2], wd = wgt[g][3];
      float s0 = wa.x * h0.x + wa.y * h0.y + wa.z * h0.z + wa.w * h0.w;
      float s1 = wb2.x * h1.x + wb2.y * h1.y + wb2.z * h1.z + wb2.w * h1.w;
      float s2 = wc.x * h2.x + wc.y * h2.y + wc.z * h2.z + wc.w * h2.w;
      float s3 = wd.x * h3.x + wd.y * h3.y + wd.z * h3.z + wd.w * h3.w;
      pg[g] = (s0 + s1) + (s2 + s3);
    }
    part[0 * 256 + w * 64 + l] = pg[0];
    part[1 * 256 + w * 64 + l] = pg[1];
    part[2 * 256 + w * 64 + l] = pg[2];
    __syncthreads();  // B: partials ready
    float ar = br + (part[0 * 256 + l] + part[0 * 256 + 64 + l]) + (part[0 * 256 + 128 + l] + part[0 * 256 + 192 + l]);
    float az = bz + (part[1 * 256 + l] + part[1 * 256 + 64 + l]) + (part[1 * 256 + 128 + l] + part[1 * 256 + 192 + l]);
    float an = bn + (part[2 * 256 + l] + part[2 * 256 + 64 + l]) + (part[2 * 256 + 128 + l] + part[2 * 256 + 192 + l]);
    float rg = sigmoidf_(xr + ar);
    float zg = sigmoidf_(xz + az);
    float ng = tanhf_(xn + rg * an);
    h = (1.f - zg) * ng + zg * h;  // identical on all 4 waves
    if (w == 0) {
      hbuf[l] = h;
      out[(size_t)(b * Sn + tt) * (2 * Hn) + dirOff + l] = h;
    }
    tt += stp;
    xr = nxr; xz = nxz; xn = nxn;
  }
}

// ---------------- K3: qkv projection -----------------------------------------
__global__ __launch_bounds__(256) void qkv_kernel(const float* __restrict__ in2,
                                                  const float* __restrict__ Wqkv,
                                                  const float* __restrict__ bqkv,
                                                  float* __restrict__ qb,
                                                  float* __restrict__ kb,
                                                  float* __restrict__ vb) {
  __shared__ float Ws[96 * 32];
  __shared__ float bs[96];
  const int tid = threadIdx.x;
  for (int i = tid; i < 96 * 32; i += 256) Ws[i] = Wqkv[i];
  if (tid < 96) bs[tid] = bqkv[tid];
  __syncthreads();
  const int idx = blockIdx.x * 256 + tid;
  float x[32];
#pragma unroll
  for (int d4 = 0; d4 < 8; ++d4) {
    float4 v = *(const float4*)&in2[(size_t)idx * 32 + d4 * 4];
    x[d4 * 4 + 0] = v.x; x[d4 * 4 + 1] = v.y; x[d4 * 4 + 2] = v.z; x[d4 * 4 + 3] = v.w;
  }
  for (int g = 0; g < 96; ++g) {
    float a = bs[g];
#pragma unroll
    for (int d = 0; d < 32; ++d) a += x[d] * Ws[g * 32 + d];
    float* dst = (g < 32) ? qb : ((g < 64) ? kb : vb);
    dst[(size_t)idx * 32 + (g & 31)] = a;
  }
}

// ---------------- K4: fused single-head attention + out_proj -----------------
__global__ __launch_bounds__(256) void attn_kernel(const float* __restrict__ qb,
                                                   const float* __restrict__ kb,
                                                   const float* __restrict__ vb,
                                                   const float* __restrict__ Wout,
                                                   const float* __restrict__ bout,
                                                   float* __restrict__ attn) {
  __shared__ float Ws[32 * 32];
  __shared__ float bs[32];
  const int tid = threadIdx.x;
  for (int i = tid; i < 1024; i += 256) Ws[i] = Wout[i];
  if (tid < 32) bs[tid] = bout[tid];
  __syncthreads();
  const int idx = blockIdx.x * 256 + tid;
  const int b = idx >> 9;
  float q[32];
#pragma unroll
  for (int d4 = 0; d4 < 8; ++d4) {
    float4 v = *(const float4*)&qb[(size_t)idx * 32 + d4 * 4];
    q[d4 * 4 + 0] = v.x; q[d4 * 4 + 1] = v.y; q[d4 * 4 + 2] = v.z; q[d4 * 4 + 3] = v.w;
  }
  const float scale = 0.17677669529663687f;
  float m = -1e30f, lsum = 0.f;
  float acc[32] = {};
  for (int kk = 0; kk < Sn; ++kk) {
    const float4* kr = (const float4*)&kb[(size_t)(b * Sn + kk) * 32];
    float s = 0.f;
#pragma unroll
    for (int d4 = 0; d4 < 8; ++d4) {
      float4 kv = kr[d4];
      s += q[d4 * 4 + 0] * kv.x + q[d4 * 4 + 1] * kv.y + q[d4 * 4 + 2] * kv.z + q[d4 * 4 + 3] * kv.w;
    }
    s *= scale;
    float mn = fmaxf(m, s);
    float e1 = __expf(m - mn);
    float p = __expf(s - mn);
    lsum = lsum * e1 + p;
    const float4* vr = (const float4*)&vb[(size_t)(b * Sn + kk) * 32];
#pragma unroll
    for (int d4 = 0; d4 < 8; ++d4) {
      float4 vv = vr[d4];
      acc[d4 * 4 + 0] = acc[d4 * 4 + 0] * e1 + p * vv.x;
      acc[d4 * 4 + 1] = acc[d4 * 4 + 1] * e1 + p * vv.y;
      acc[d4 * 4 + 2] = acc[d4 * 4 + 2] * e1 + p * vv.z;
      acc[d4 * 4 + 3] = acc[d4 * 4 + 3] * e1 + p * vv.w;
    }
    m = mn;
  }
  const float inv = 1.f / lsum;
  float a[32];
#pragma unroll
  for (int d = 0; d < 32; ++d) a[d] = acc[d] * inv;
#pragma unroll
  for (int j = 0; j < 32; ++j) {
    float o = bs[j];
#pragma unroll
    for (int d = 0; d < 32; ++d) o += a[d] * Ws[j * 32 + d];
    attn[(size_t)idx * 32 + j] = o;
  }
}

// ---------------- K5: Wcomb = Wdense(128x16) @ Wfuse_top(16x16) --------------
__global__ __launch_bounds__(256) void wcomb_kernel(const float* __restrict__ Wdense,
                                                    const float* __restrict__ Wfuse,
                                                    float* __restrict__ wcomb) {
  int e = blockIdx.x * 256 + threadIdx.x;
  int i = e >> 4, j = e & 15;
  float a = 0.f;
#pragma unroll
  for (int c = 0; c < 16; ++c) a += Wdense[i * 16 + c] * Wfuse[c * 16 + j];
  wcomb[e] = a;
}

// ---------------- K6: emissions ----------------------------------------------
__global__ __launch_bounds__(256) void emis_kernel(const float* __restrict__ lstm,
                                                   const float* __restrict__ attn,
                                                   const float* __restrict__ wcomb,
                                                   const float* __restrict__ Wfuse,
                                                   float* __restrict__ emis) {
  __shared__ float Wc[128 * 16];
  __shared__ float Wf2[32 * 16];
  const int tid = threadIdx.x;
  for (int i = tid; i < 2048; i += 256) Wc[i] = wcomb[i];
  for (int i = tid; i < 512; i += 256) Wf2[i] = Wfuse[16 * 16 + i];
  __syncthreads();
  const int idx = blockIdx.x * 256 + tid;
  float acc[16] = {};
  for (int i = 0; i < 128; i += 4) {
    float4 lv = *(const float4*)&lstm[(size_t)idx * 128 + i];
    float ll[4] = {lv.x, lv.y, lv.z, lv.w};
#pragma unroll
    for (int u = 0; u < 4; ++u)
#pragma unroll
      for (int j = 0; j < 16; ++j) acc[j] += ll[u] * Wc[(i + u) * 16 + j];
  }
  for (int d = 0; d < 32; d += 4) {
    float4 av = *(const float4*)&attn[(size_t)idx * 32 + d];
    float aa[4] = {av.x, av.y, av.z, av.w};
#pragma unroll
    for (int u = 0; u < 4; ++u)
#pragma unroll
      for (int j = 0; j < 16; ++j) acc[j] += aa[u] * Wf2[(d + u) * 16 + j];
  }
#pragma unroll
  for (int j = 0; j < 16; j += 4) {
    float4 o = {acc[j], acc[j + 1], acc[j + 2], acc[j + 3]};
    *(float4*)&emis[(size_t)idx * 16 + j] = o;
  }
}

// ---------------- K7: CRF numerator ------------------------------------------
__global__ __launch_bounds__(64) void numer_kernel(const float* __restrict__ emis,
                                                   const int* __restrict__ tgt,
                                                   const float* __restrict__ cstart,
                                                   const float* __restrict__ cend,
                                                   const float* __restrict__ ctrans,
                                                   float* __restrict__ numer) {
  const int b = blockIdx.x, l = threadIdx.x;
  float ssum = 0.f;
  for (int t = l; t < Sn; t += 64) {
    int tg = tgt[b * Sn + t];
    ssum += emis[(size_t)(b * Sn + t) * Tn + tg];
    if (t + 1 < Sn) {
      int tg2 = tgt[b * Sn + t + 1];
      ssum += ctrans[tg * Tn + tg2];
    }
  }
  if (l == 0) ssum += cstart[tgt[b * Sn]] + cend[tgt[b * Sn + Sn - 1]];
  for (int off = 32; off > 0; off >>= 1) ssum += __shfl_down(ssum, off);
  if (l == 0) numer[b] = ssum;
}

// ---------------- K8: CRF forward (denominator) ------------------------------
__global__ __launch_bounds__(64) void denom_kernel(const float* __restrict__ emis,
                                                   const float* __restrict__ cstart,
                                                   const float* __restrict__ cend,
                                                   const float* __restrict__ ctrans,
                                                   float* __restrict__ denom) {
  __shared__ float sc[16];
  __shared__ float fin[16];
  const int b = blockIdx.x;
  const int j = threadIdx.x & 15;
  float tr[16];
#pragma unroll
  for (int i = 0; i < 16; ++i) tr[i] = ctrans[i * 16 + j];
  float s = cstart[j] + emis[(size_t)(b * Sn) * Tn + j];
  for (int t = 1; t < Sn; ++t) {
    if (threadIdx.x < 16) sc[j] = s;
    __syncthreads();
    float v[16];
    float m = -1e30f;
#pragma unroll
    for (int i = 0; i < 16; ++i) { v[i] = sc[i] + tr[i]; m = fmaxf(m, v[i]); }
    float es = 0.f;
#pragma unroll
    for (int i = 0; i < 16; ++i) es += __expf(v[i] - m);
    s = emis[(size_t)(b * Sn + t) * Tn + j] + m + __logf(es);
    __syncthreads();
  }
  if (threadIdx.x < 16) fin[j] = s + cend[j];
  __syncthreads();
  if (threadIdx.x == 0) {
    float m = -1e30f;
#pragma unroll
    for (int i = 0; i < 16; ++i) m = fmaxf(m, fin[i]);
    float es = 0.f;
#pragma unroll
    for (int i = 0; i < 16; ++i) es += __expf(fin[i] - m);
    denom[b] = m + __logf(es);
  }
}

// ---------------- K9: final scalar -------------------------------------------
__global__ __launch_bounds__(64) void final_kernel(const float* __restrict__ numer,
                                                   const float* __restrict__ denom,
                                                   float* __restrict__ out) {
  const int l = threadIdx.x;
  float d = denom[l] - numer[l];
  for (int off = 32; off > 0; off >>= 1) d += __shfl_down(d, off);
  if (l == 0) out[0] = d * (1.f / 64.f);
}

extern "C" void kernel_launch(void* const* d_in, const int* in_sizes, int n_in,
                              void* d_out, int out_size, void* d_ws, size_t ws_size,
                              hipStream_t stream) {
  (void)in_sizes; (void)n_in; (void)out_size; (void)ws_size;
  const float* bert = (const float*)d_in[0];
  const float* in2 = (const float*)d_in[1];
  const int* tgt = (const int*)d_in[2];
  const float* Wih_f = (const float*)d_in[3];
  const float* Whh_f = (const float*)d_in[4];
  const float* bih_f = (const float*)d_in[5];
  const float* bhh_f = (const float*)d_in[6];
  const float* Wih_b = (const float*)d_in[7];
  const float* Whh_b = (const float*)d_in[8];
  const float* bih_b = (const float*)d_in[9];
  const float* bhh_b = (const float*)d_in[10];
  const float* Wdense = (const float*)d_in[11];
  const float* in_proj_w = (const float*)d_in[12];
  const float* in_proj_b = (const float*)d_in[13];
  const float* out_proj_w = (const float*)d_in[14];
  const float* out_proj_b = (const float*)d_in[15];
  const float* Wfuse = (const float*)d_in[16];
  const float* cstart = (const float*)d_in[17];
  const float* cend = (const float*)d_in[18];
  const float* ctrans = (const float*)d_in[19];

  float* ws = (float*)d_ws;
  float* C = ws;                                    // B*S*384
  float* lstm = C + (size_t)Bn * Sn * 384;          // B*S*128
  float* qb = lstm + (size_t)Bn * Sn * 2 * Hn;      // B*S*32
  float* kb = qb + (size_t)Bn * Sn * Pn;
  float* vb = kb + (size_t)Bn * Sn * Pn;
  float* attn = vb + (size_t)Bn * Sn * Pn;
  float* emis = attn + (size_t)Bn * Sn * Pn;        // B*S*16
  float* wcomb = emis + (size_t)Bn * Sn * Tn;       // 2048
  float* numer = wcomb + 128 * 16;                  // 64
  float* denom = numer + Bn;                        // 64

  dim3 gg(3, Bn * Sn / 128);
  gemm_mfma<<<gg, 256, 0, stream>>>(bert, Wih_f, Wih_b, bih_f, bih_b, C);
  qkv_kernel<<<Bn * Sn / 256, 256, 0, stream>>>(in2, in_proj_w, in_proj_b, qb, kb, vb);
  wcomb_kernel<<<8, 256, 0, stream>>>(Wdense, Wfuse, wcomb);
  gru_kernel<<<2 * Bn, 256, 0, stream>>>(C, Whh_f, bhh_f, Whh_b, bhh_b, lstm);
  attn_kernel<<<Bn * Sn / 256, 256, 0, stream>>>(qb, kb, vb, out_proj_w, out_proj_b, attn);
  emis_kernel<<<Bn * Sn / 256, 256, 0, stream>>>(lstm, attn, wcomb, Wfuse, emis);
  numer_kernel<<<Bn, 64, 0, stream>>>(emis, tgt, cstart, cend, ctrans, numer);
  denom_kernel<<<Bn, 64, 0, stream>>>(emis, cstart, cend, ctrans, denom);
  final_kernel<<<1, 64, 0, stream>>>(numer, denom, (float*)d_out);
}

// Round 4
// 984.974 us; speedup vs baseline: 1.3139x; 1.0858x over previous
//
#include <hip/hip_runtime.h>

#define Bn 64
#define Sn 512
#define EB 768
#define Hn 64
#define G3 192
#define Tn 16
#define Pn 32

__device__ __forceinline__ float sigmoidf_(float x) { return 1.f / (1.f + __expf(-x)); }
__device__ __forceinline__ float tanhf_(float x) { return 1.f - 2.f / (__expf(2.f * x) + 1.f); }

__device__ __forceinline__ unsigned short f2bf(float x) {
  union { float f; unsigned u; } v; v.f = x;
  unsigned r = v.u + 0x7fff + ((v.u >> 16) & 1);  // RNE
  return (unsigned short)(r >> 16);
}

typedef __attribute__((ext_vector_type(8))) short short8;
typedef __attribute__((ext_vector_type(4))) float f32x4;

// ---------------- K1: C(32768x384) = bert(32768x768) @ [Wf;Wb]^T + bias, bf16 MFMA
__global__ __launch_bounds__(256) void gemm_mfma(const float* __restrict__ A,
                                                 const float* __restrict__ Wf,
                                                 const float* __restrict__ Wb,
                                                 const float* __restrict__ bf,
                                                 const float* __restrict__ bb,
                                                 float* __restrict__ C) {
  __shared__ __align__(16) unsigned short As[128 * 40];
  __shared__ __align__(16) unsigned short Bs[128 * 40];
  const int tid = threadIdx.x;
  const int n0 = blockIdx.x * 128;
  const int m0 = blockIdx.y * 128;
  const int wv = tid >> 6;
  const int lane = tid & 63;
  const int wm = (wv >> 1) * 64, wn = (wv & 1) * 64;
  const int fr = lane & 15, fq = lane >> 4;
  const int srow = tid >> 1;
  const int shalf = (tid & 1) * 16;
  const int bcol = n0 + srow;
  const float* Wrow = (bcol < G3) ? (Wf + (size_t)bcol * EB) : (Wb + (size_t)(bcol - G3) * EB);
  const float* Arow = A + (size_t)(m0 + srow) * EB;
  f32x4 acc[4][4];
#pragma unroll
  for (int i = 0; i < 4; ++i)
#pragma unroll
    for (int j = 0; j < 4; ++j) acc[i][j] = (f32x4){0.f, 0.f, 0.f, 0.f};

  for (int k0 = 0; k0 < EB; k0 += 32) {
    float4 a0 = *(const float4*)&Arow[k0 + shalf + 0];
    float4 a1 = *(const float4*)&Arow[k0 + shalf + 4];
    float4 a2 = *(const float4*)&Arow[k0 + shalf + 8];
    float4 a3 = *(const float4*)&Arow[k0 + shalf + 12];
    float4 b0 = *(const float4*)&Wrow[k0 + shalf + 0];
    float4 b1 = *(const float4*)&Wrow[k0 + shalf + 4];
    float4 b2 = *(const float4*)&Wrow[k0 + shalf + 8];
    float4 b3 = *(const float4*)&Wrow[k0 + shalf + 12];
    __syncthreads();
    short8 pa, pb;
    pa[0] = f2bf(a0.x); pa[1] = f2bf(a0.y); pa[2] = f2bf(a0.z); pa[3] = f2bf(a0.w);
    pa[4] = f2bf(a1.x); pa[5] = f2bf(a1.y); pa[6] = f2bf(a1.z); pa[7] = f2bf(a1.w);
    *(short8*)&As[srow * 40 + shalf] = pa;
    pa[0] = f2bf(a2.x); pa[1] = f2bf(a2.y); pa[2] = f2bf(a2.z); pa[3] = f2bf(a2.w);
    pa[4] = f2bf(a3.x); pa[5] = f2bf(a3.y); pa[6] = f2bf(a3.z); pa[7] = f2bf(a3.w);
    *(short8*)&As[srow * 40 + shalf + 8] = pa;
    pb[0] = f2bf(b0.x); pb[1] = f2bf(b0.y); pb[2] = f2bf(b0.z); pb[3] = f2bf(b0.w);
    pb[4] = f2bf(b1.x); pb[5] = f2bf(b1.y); pb[6] = f2bf(b1.z); pb[7] = f2bf(b1.w);
    *(short8*)&Bs[srow * 40 + shalf] = pb;
    pb[0] = f2bf(b2.x); pb[1] = f2bf(b2.y); pb[2] = f2bf(b2.z); pb[3] = f2bf(b2.w);
    pb[4] = f2bf(b3.x); pb[5] = f2bf(b3.y); pb[6] = f2bf(b3.z); pb[7] = f2bf(b3.w);
    *(short8*)&Bs[srow * 40 + shalf + 8] = pb;
    __syncthreads();
    short8 af[4], bfv[4];
#pragma unroll
    for (int i = 0; i < 4; ++i) af[i] = *(short8*)&As[(wm + i * 16 + fr) * 40 + fq * 8];
#pragma unroll
    for (int j = 0; j < 4; ++j) bfv[j] = *(short8*)&Bs[(wn + j * 16 + fr) * 40 + fq * 8];
#pragma unroll
    for (int i = 0; i < 4; ++i)
#pragma unroll
      for (int j = 0; j < 4; ++j)
        acc[i][j] = __builtin_amdgcn_mfma_f32_16x16x32_bf16(af[i], bfv[j], acc[i][j], 0, 0, 0);
  }
#pragma unroll
  for (int j = 0; j < 4; ++j) {
    int col = n0 + wn + j * 16 + fr;
    float bias = (col < G3) ? bf[col] : bb[col - G3];
#pragma unroll
    for (int i = 0; i < 4; ++i) {
      int rowb = m0 + wm + i * 16 + fq * 4;
#pragma unroll
      for (int rg = 0; rg < 4; ++rg)
        C[(size_t)(rowb + rg) * 384 + col] = acc[i][j][rg] + bias;
    }
  }
}

// ---------------- K2: Bi-GRU, 4 waves per (b,dir) -----------------------------
// Wave w owns output rows [16w,16w+16). Lane (r,kc) = r*4+... lane = r<<2|kc
// computes k-slice [16kc,16kc+16) of row 16w+r; in-wave shfl_xor reduction.
// Weights pinned in VGPRs via asm. One barrier/step, double-buffered h in LDS.
__global__ __launch_bounds__(256, 1) void gru_kernel(const float* __restrict__ C,
                                                     const float* __restrict__ Whh_f,
                                                     const float* __restrict__ bhh_f,
                                                     const float* __restrict__ Whh_b,
                                                     const float* __restrict__ bhh_b,
                                                     float* __restrict__ out) {
  __shared__ __align__(16) float hbuf[2][64];
  const int wg = blockIdx.x;
  const int rev = (wg >= Bn) ? 1 : 0;
  const int b = wg & (Bn - 1);
  const int tid = threadIdx.x;
  const int w = tid >> 6;
  const int lane = tid & 63;
  const int r = lane >> 2;
  const int kc = lane & 3;
  const int row = 16 * w + r;   // 0..63
  const int k0 = 16 * kc;       // 0,16,32,48
  const float* Whh = rev ? Whh_b : Whh_f;
  const float* bhh = rev ? bhh_b : bhh_f;
  const int colBase = rev ? G3 : 0;
  const int dirOff = rev ? Hn : 0;
  float4 wv[3][4];
#pragma unroll
  for (int g = 0; g < 3; ++g)
#pragma unroll
    for (int q = 0; q < 4; ++q) {
      wv[g][q] = *(const float4*)&Whh[(size_t)(g * 64 + row) * 64 + k0 + 4 * q];
      asm volatile("" : "+v"(wv[g][q].x), "+v"(wv[g][q].y), "+v"(wv[g][q].z), "+v"(wv[g][q].w));
    }
  const float brr = bhh[row], bzz = bhh[64 + row], bnn = bhh[128 + row];
  if (tid < 64) { hbuf[0][tid] = 0.f; hbuf[1][tid] = 0.f; }
  float h = 0.f;  // h_{t-1} for my row
  int tt = rev ? (Sn - 1) : 0;
  const int stp = rev ? -1 : 1;
  const float* x0 = C + (size_t)(b * Sn + tt) * 384 + colBase;
  float xr = x0[row], xz = x0[64 + row], xn = x0[128 + row];
  __syncthreads();
  for (int t = 0; t < Sn; ++t) {
    const int p = t & 1;
    float4 ha = *(const float4*)&hbuf[p][k0 + 0];
    float4 hb = *(const float4*)&hbuf[p][k0 + 4];
    float4 hc = *(const float4*)&hbuf[p][k0 + 8];
    float4 hd = *(const float4*)&hbuf[p][k0 + 12];
    float nxr = 0.f, nxz = 0.f, nxn = 0.f;
    if (t + 1 < Sn) {
      const float* xq = C + (size_t)(b * Sn + tt + stp) * 384 + colBase;
      nxr = xq[row]; nxz = xq[64 + row]; nxn = xq[128 + row];
    }
    float dr, dz, dn;
    {
      float4 wa, wbv, wc, wd;
      wa = wv[0][0]; wbv = wv[0][1]; wc = wv[0][2]; wd = wv[0][3];
      dr = (wa.x * ha.x + wa.y * ha.y + wa.z * ha.z + wa.w * ha.w)
         + (wbv.x * hb.x + wbv.y * hb.y + wbv.z * hb.z + wbv.w * hb.w)
         + (wc.x * hc.x + wc.y * hc.y + wc.z * hc.z + wc.w * hc.w)
         + (wd.x * hd.x + wd.y * hd.y + wd.z * hd.z + wd.w * hd.w);
      wa = wv[1][0]; wbv = wv[1][1]; wc = wv[1][2]; wd = wv[1][3];
      dz = (wa.x * ha.x + wa.y * ha.y + wa.z * ha.z + wa.w * ha.w)
         + (wbv.x * hb.x + wbv.y * hb.y + wbv.z * hb.z + wbv.w * hb.w)
         + (wc.x * hc.x + wc.y * hc.y + wc.z * hc.z + wc.w * hc.w)
         + (wd.x * hd.x + wd.y * hd.y + wd.z * hd.z + wd.w * hd.w);
      wa = wv[2][0]; wbv = wv[2][1]; wc = wv[2][2]; wd = wv[2][3];
      dn = (wa.x * ha.x + wa.y * ha.y + wa.z * ha.z + wa.w * ha.w)
         + (wbv.x * hb.x + wbv.y * hb.y + wbv.z * hb.z + wbv.w * hb.w)
         + (wc.x * hc.x + wc.y * hc.y + wc.z * hc.z + wc.w * hc.w)
         + (wd.x * hd.x + wd.y * hd.y + wd.z * hd.z + wd.w * hd.w);
    }
    dr += __shfl_xor(dr, 1); dr += __shfl_xor(dr, 2);
    dz += __shfl_xor(dz, 1); dz += __shfl_xor(dz, 2);
    dn += __shfl_xor(dn, 1); dn += __shfl_xor(dn, 2);
    float rg = sigmoidf_(xr + brr + dr);
    float zg = sigmoidf_(xz + bzz + dz);
    float ng = tanhf_(xn + rg * (bnn + dn));
    h = (1.f - zg) * ng + zg * h;
    if (kc == 0) {
      hbuf[p ^ 1][row] = h;
      out[(size_t)(b * Sn + tt) * (2 * Hn) + dirOff + row] = h;
    }
    __syncthreads();
    tt += stp;
    xr = nxr; xz = nxz; xn = nxn;
  }
}

// ---------------- K3: qkv projection -----------------------------------------
__global__ __launch_bounds__(256) void qkv_kernel(const float* __restrict__ in2,
                                                  const float* __restrict__ Wqkv,
                                                  const float* __restrict__ bqkv,
                                                  float* __restrict__ qb,
                                                  float* __restrict__ kb,
                                                  float* __restrict__ vb) {
  __shared__ float Ws[96 * 32];
  __shared__ float bs[96];
  const int tid = threadIdx.x;
  for (int i = tid; i < 96 * 32; i += 256) Ws[i] = Wqkv[i];
  if (tid < 96) bs[tid] = bqkv[tid];
  __syncthreads();
  const int idx = blockIdx.x * 256 + tid;
  float x[32];
#pragma unroll
  for (int d4 = 0; d4 < 8; ++d4) {
    float4 v = *(const float4*)&in2[(size_t)idx * 32 + d4 * 4];
    x[d4 * 4 + 0] = v.x; x[d4 * 4 + 1] = v.y; x[d4 * 4 + 2] = v.z; x[d4 * 4 + 3] = v.w;
  }
  for (int g = 0; g < 96; ++g) {
    float a = bs[g];
#pragma unroll
    for (int d = 0; d < 32; ++d) a += x[d] * Ws[g * 32 + d];
    float* dst = (g < 32) ? qb : ((g < 64) ? kb : vb);
    dst[(size_t)idx * 32 + (g & 31)] = a;
  }
}

// ---------------- K4: fused single-head attention + out_proj -----------------
__global__ __launch_bounds__(256) void attn_kernel(const float* __restrict__ qb,
                                                   const float* __restrict__ kb,
                                                   const float* __restrict__ vb,
                                                   const float* __restrict__ Wout,
                                                   const float* __restrict__ bout,
                                                   float* __restrict__ attn) {
  __shared__ float Ws[32 * 32];
  __shared__ float bs[32];
  const int tid = threadIdx.x;
  for (int i = tid; i < 1024; i += 256) Ws[i] = Wout[i];
  if (tid < 32) bs[tid] = bout[tid];
  __syncthreads();
  const int idx = blockIdx.x * 256 + tid;
  const int b = idx >> 9;
  float q[32];
#pragma unroll
  for (int d4 = 0; d4 < 8; ++d4) {
    float4 v = *(const float4*)&qb[(size_t)idx * 32 + d4 * 4];
    q[d4 * 4 + 0] = v.x; q[d4 * 4 + 1] = v.y; q[d4 * 4 + 2] = v.z; q[d4 * 4 + 3] = v.w;
  }
  const float scale = 0.17677669529663687f;
  float m = -1e30f, lsum = 0.f;
  float acc[32] = {};
  for (int kk = 0; kk < Sn; ++kk) {
    const float4* kr = (const float4*)&kb[(size_t)(b * Sn + kk) * 32];
    float s = 0.f;
#pragma unroll
    for (int d4 = 0; d4 < 8; ++d4) {
      float4 kv = kr[d4];
      s += q[d4 * 4 + 0] * kv.x + q[d4 * 4 + 1] * kv.y + q[d4 * 4 + 2] * kv.z + q[d4 * 4 + 3] * kv.w;
    }
    s *= scale;
    float mn = fmaxf(m, s);
    float e1 = __expf(m - mn);
    float p = __expf(s - mn);
    lsum = lsum * e1 + p;
    const float4* vr = (const float4*)&vb[(size_t)(b * Sn + kk) * 32];
#pragma unroll
    for (int d4 = 0; d4 < 8; ++d4) {
      float4 vv = vr[d4];
      acc[d4 * 4 + 0] = acc[d4 * 4 + 0] * e1 + p * vv.x;
      acc[d4 * 4 + 1] = acc[d4 * 4 + 1] * e1 + p * vv.y;
      acc[d4 * 4 + 2] = acc[d4 * 4 + 2] * e1 + p * vv.z;
      acc[d4 * 4 + 3] = acc[d4 * 4 + 3] * e1 + p * vv.w;
    }
    m = mn;
  }
  const float inv = 1.f / lsum;
  float a[32];
#pragma unroll
  for (int d = 0; d < 32; ++d) a[d] = acc[d] * inv;
#pragma unroll
  for (int j = 0; j < 32; ++j) {
    float o = bs[j];
#pragma unroll
    for (int d = 0; d < 32; ++d) o += a[d] * Ws[j * 32 + d];
    attn[(size_t)idx * 32 + j] = o;
  }
}

// ---------------- K5: Wcomb = Wdense(128x16) @ Wfuse_top(16x16) --------------
__global__ __launch_bounds__(256) void wcomb_kernel(const float* __restrict__ Wdense,
                                                    const float* __restrict__ Wfuse,
                                                    float* __restrict__ wcomb) {
  int e = blockIdx.x * 256 + threadIdx.x;
  int i = e >> 4, j = e & 15;
  float a = 0.f;
#pragma unroll
  for (int c = 0; c < 16; ++c) a += Wdense[i * 16 + c] * Wfuse[c * 16 + j];
  wcomb[e] = a;
}

// ---------------- K6: emissions ----------------------------------------------
__global__ __launch_bounds__(256) void emis_kernel(const float* __restrict__ lstm,
                                                   const float* __restrict__ attn,
                                                   const float* __restrict__ wcomb,
                                                   const float* __restrict__ Wfuse,
                                                   float* __restrict__ emis) {
  __shared__ float Wc[128 * 16];
  __shared__ float Wf2[32 * 16];
  const int tid = threadIdx.x;
  for (int i = tid; i < 2048; i += 256) Wc[i] = wcomb[i];
  for (int i = tid; i < 512; i += 256) Wf2[i] = Wfuse[16 * 16 + i];
  __syncthreads();
  const int idx = blockIdx.x * 256 + tid;
  float acc[16] = {};
  for (int i = 0; i < 128; i += 4) {
    float4 lv = *(const float4*)&lstm[(size_t)idx * 128 + i];
    float ll[4] = {lv.x, lv.y, lv.z, lv.w};
#pragma unroll
    for (int u = 0; u < 4; ++u)
#pragma unroll
      for (int j = 0; j < 16; ++j) acc[j] += ll[u] * Wc[(i + u) * 16 + j];
  }
  for (int d = 0; d < 32; d += 4) {
    float4 av = *(const float4*)&attn[(size_t)idx * 32 + d];
    float aa[4] = {av.x, av.y, av.z, av.w};
#pragma unroll
    for (int u = 0; u < 4; ++u)
#pragma unroll
      for (int j = 0; j < 16; ++j) acc[j] += aa[u] * Wf2[(d + u) * 16 + j];
  }
#pragma unroll
  for (int j = 0; j < 16; j += 4) {
    float4 o = {acc[j], acc[j + 1], acc[j + 2], acc[j + 3]};
    *(float4*)&emis[(size_t)idx * 16 + j] = o;
  }
}

// ---------------- K7: CRF numerator ------------------------------------------
__global__ __launch_bounds__(64) void numer_kernel(const float* __restrict__ emis,
                                                   const int* __restrict__ tgt,
                                                   const float* __restrict__ cstart,
                                                   const float* __restrict__ cend,
                                                   const float* __restrict__ ctrans,
                                                   float* __restrict__ numer) {
  const int b = blockIdx.x, l = threadIdx.x;
  float ssum = 0.f;
  for (int t = l; t < Sn; t += 64) {
    int tg = tgt[b * Sn + t];
    ssum += emis[(size_t)(b * Sn + t) * Tn + tg];
    if (t + 1 < Sn) {
      int tg2 = tgt[b * Sn + t + 1];
      ssum += ctrans[tg * Tn + tg2];
    }
  }
  if (l == 0) ssum += cstart[tgt[b * Sn]] + cend[tgt[b * Sn + Sn - 1]];
  for (int off = 32; off > 0; off >>= 1) ssum += __shfl_down(ssum, off);
  if (l == 0) numer[b] = ssum;
}

// ---------------- K8: CRF forward (denominator), shfl-only --------------------
// lane = g*16+j (g=0..3, j=0..15). Lane handles i in [4g,4g+4).
__global__ __launch_bounds__(64) void denom_kernel(const float* __restrict__ emis,
                                                   const float* __restrict__ cstart,
                                                   const float* __restrict__ cend,
                                                   const float* __restrict__ ctrans,
                                                   float* __restrict__ denom) {
  const int b = blockIdx.x;
  const int lane = threadIdx.x;
  const int g = lane >> 4;
  const int j = lane & 15;
  const int i0 = 4 * g;
  float tr0 = ctrans[(i0 + 0) * Tn + j];
  float tr1 = ctrans[(i0 + 1) * Tn + j];
  float tr2 = ctrans[(i0 + 2) * Tn + j];
  float tr3 = ctrans[(i0 + 3) * Tn + j];
  float s = cstart[j] + emis[(size_t)(b * Sn) * Tn + j];  // replicated over g
  float em = emis[(size_t)(b * Sn + 1) * Tn + j];
  for (int t = 1; t < Sn; ++t) {
    float s0 = __shfl(s, i0 + 0);
    float s1 = __shfl(s, i0 + 1);
    float s2 = __shfl(s, i0 + 2);
    float s3 = __shfl(s, i0 + 3);
    float v0 = s0 + tr0, v1 = s1 + tr1, v2 = s2 + tr2, v3 = s3 + tr3;
    float m = fmaxf(fmaxf(v0, v1), fmaxf(v2, v3));
    m = fmaxf(m, __shfl_xor(m, 16));
    m = fmaxf(m, __shfl_xor(m, 32));
    float e = __expf(v0 - m) + __expf(v1 - m) + __expf(v2 - m) + __expf(v3 - m);
    e += __shfl_xor(e, 16);
    e += __shfl_xor(e, 32);
    float em_cur = em;
    if (t + 1 < Sn) em = emis[(size_t)(b * Sn + t + 1) * Tn + j];
    s = em_cur + m + __logf(e);
  }
  float f = s + cend[j];
  float m = f;
  m = fmaxf(m, __shfl_xor(m, 1));
  m = fmaxf(m, __shfl_xor(m, 2));
  m = fmaxf(m, __shfl_xor(m, 4));
  m = fmaxf(m, __shfl_xor(m, 8));
  float e = __expf(f - m);
  e += __shfl_xor(e, 1);
  e += __shfl_xor(e, 2);
  e += __shfl_xor(e, 4);
  e += __shfl_xor(e, 8);
  if (lane == 0) denom[b] = m + __logf(e);
}

// ---------------- K9: final scalar -------------------------------------------
__global__ __launch_bounds__(64) void final_kernel(const float* __restrict__ numer,
                                                   const float* __restrict__ denom,
                                                   float* __restrict__ out) {
  const int l = threadIdx.x;
  float d = denom[l] - numer[l];
  for (int off = 32; off > 0; off >>= 1) d += __shfl_down(d, off);
  if (l == 0) out[0] = d * (1.f / 64.f);
}

extern "C" void kernel_launch(void* const* d_in, const int* in_sizes, int n_in,
                              void* d_out, int out_size, void* d_ws, size_t ws_size,
                              hipStream_t stream) {
  (void)in_sizes; (void)n_in; (void)out_size; (void)ws_size;
  const float* bert = (const float*)d_in[0];
  const float* in2 = (const float*)d_in[1];
  const int* tgt = (const int*)d_in[2];
  const float* Wih_f = (const float*)d_in[3];
  const float* Whh_f = (const float*)d_in[4];
  const float* bih_f = (const float*)d_in[5];
  const float* bhh_f = (const float*)d_in[6];
  const float* Wih_b = (const float*)d_in[7];
  const float* Whh_b = (const float*)d_in[8];
  const float* bih_b = (const float*)d_in[9];
  const float* bhh_b = (const float*)d_in[10];
  const float* Wdense = (const float*)d_in[11];
  const float* in_proj_w = (const float*)d_in[12];
  const float* in_proj_b = (const float*)d_in[13];
  const float* out_proj_w = (const float*)d_in[14];
  const float* out_proj_b = (const float*)d_in[15];
  const float* Wfuse = (const float*)d_in[16];
  const float* cstart = (const float*)d_in[17];
  const float* cend = (const float*)d_in[18];
  const float* ctrans = (const float*)d_in[19];

  float* ws = (float*)d_ws;
  float* C = ws;                                    // B*S*384
  float* lstm = C + (size_t)Bn * Sn * 384;          // B*S*128
  float* qb = lstm + (size_t)Bn * Sn * 2 * Hn;      // B*S*32
  float* kb = qb + (size_t)Bn * Sn * Pn;
  float* vb = kb + (size_t)Bn * Sn * Pn;
  float* attn = vb + (size_t)Bn * Sn * Pn;
  float* emis = attn + (size_t)Bn * Sn * Pn;        // B*S*16
  float* wcomb = emis + (size_t)Bn * Sn * Tn;       // 2048
  float* numer = wcomb + 128 * 16;                  // 64
  float* denom = numer + Bn;                        // 64

  dim3 gg(3, Bn * Sn / 128);
  gemm_mfma<<<gg, 256, 0, stream>>>(bert, Wih_f, Wih_b, bih_f, bih_b, C);
  qkv_kernel<<<Bn * Sn / 256, 256, 0, stream>>>(in2, in_proj_w, in_proj_b, qb, kb, vb);
  wcomb_kernel<<<8, 256, 0, stream>>>(Wdense, Wfuse, wcomb);
  gru_kernel<<<2 * Bn, 256, 0, stream>>>(C, Whh_f, bhh_f, Whh_b, bhh_b, lstm);
  attn_kernel<<<Bn * Sn / 256, 256, 0, stream>>>(qb, kb, vb, out_proj_w, out_proj_b, attn);
  emis_kernel<<<Bn * Sn / 256, 256, 0, stream>>>(lstm, attn, wcomb, Wfuse, emis);
  numer_kernel<<<Bn, 64, 0, stream>>>(emis, tgt, cstart, cend, ctrans, numer);
  denom_kernel<<<Bn, 64, 0, stream>>>(emis, cstart, cend, ctrans, denom);
  final_kernel<<<1, 64, 0, stream>>>(numer, denom, (float*)d_out);
}

// Round 5
// 767.535 us; speedup vs baseline: 1.6861x; 1.2833x over previous
//
#include <hip/hip_runtime.h>

#define Bn 64
#define Sn 512
#define EB 768
#define Hn 64
#define G3 192
#define Tn 16
#define Pn 32

__device__ __forceinline__ float sigmoidf_(float x) { return 1.f / (1.f + __expf(-x)); }
__device__ __forceinline__ float tanhf_(float x) { return 1.f - 2.f / (__expf(2.f * x) + 1.f); }

__device__ __forceinline__ unsigned short f2bf(float x) {
  union { float f; unsigned u; } v; v.f = x;
  unsigned r = v.u + 0x7fff + ((v.u >> 16) & 1);  // RNE
  return (unsigned short)(r >> 16);
}

typedef __attribute__((ext_vector_type(8))) short short8;
typedef __attribute__((ext_vector_type(4))) float f32x4;

// ---------------- K1: C(32768x384) = bert(32768x768) @ [Wf;Wb]^T + bias, bf16 MFMA
__global__ __launch_bounds__(256) void gemm_mfma(const float* __restrict__ A,
                                                 const float* __restrict__ Wf,
                                                 const float* __restrict__ Wb,
                                                 const float* __restrict__ bf,
                                                 const float* __restrict__ bb,
                                                 float* __restrict__ C) {
  __shared__ __align__(16) unsigned short As[128 * 40];
  __shared__ __align__(16) unsigned short Bs[128 * 40];
  const int tid = threadIdx.x;
  const int n0 = blockIdx.x * 128;
  const int m0 = blockIdx.y * 128;
  const int wv = tid >> 6;
  const int lane = tid & 63;
  const int wm = (wv >> 1) * 64, wn = (wv & 1) * 64;
  const int fr = lane & 15, fq = lane >> 4;
  const int srow = tid >> 1;
  const int shalf = (tid & 1) * 16;
  const int bcol = n0 + srow;
  const float* Wrow = (bcol < G3) ? (Wf + (size_t)bcol * EB) : (Wb + (size_t)(bcol - G3) * EB);
  const float* Arow = A + (size_t)(m0 + srow) * EB;
  f32x4 acc[4][4];
#pragma unroll
  for (int i = 0; i < 4; ++i)
#pragma unroll
    for (int j = 0; j < 4; ++j) acc[i][j] = (f32x4){0.f, 0.f, 0.f, 0.f};

  for (int k0 = 0; k0 < EB; k0 += 32) {
    float4 a0 = *(const float4*)&Arow[k0 + shalf + 0];
    float4 a1 = *(const float4*)&Arow[k0 + shalf + 4];
    float4 a2 = *(const float4*)&Arow[k0 + shalf + 8];
    float4 a3 = *(const float4*)&Arow[k0 + shalf + 12];
    float4 b0 = *(const float4*)&Wrow[k0 + shalf + 0];
    float4 b1 = *(const float4*)&Wrow[k0 + shalf + 4];
    float4 b2 = *(const float4*)&Wrow[k0 + shalf + 8];
    float4 b3 = *(const float4*)&Wrow[k0 + shalf + 12];
    __syncthreads();
    short8 pa, pb;
    pa[0] = f2bf(a0.x); pa[1] = f2bf(a0.y); pa[2] = f2bf(a0.z); pa[3] = f2bf(a0.w);
    pa[4] = f2bf(a1.x); pa[5] = f2bf(a1.y); pa[6] = f2bf(a1.z); pa[7] = f2bf(a1.w);
    *(short8*)&As[srow * 40 + shalf] = pa;
    pa[0] = f2bf(a2.x); pa[1] = f2bf(a2.y); pa[2] = f2bf(a2.z); pa[3] = f2bf(a2.w);
    pa[4] = f2bf(a3.x); pa[5] = f2bf(a3.y); pa[6] = f2bf(a3.z); pa[7] = f2bf(a3.w);
    *(short8*)&As[srow * 40 + shalf + 8] = pa;
    pb[0] = f2bf(b0.x); pb[1] = f2bf(b0.y); pb[2] = f2bf(b0.z); pb[3] = f2bf(b0.w);
    pb[4] = f2bf(b1.x); pb[5] = f2bf(b1.y); pb[6] = f2bf(b1.z); pb[7] = f2bf(b1.w);
    *(short8*)&Bs[srow * 40 + shalf] = pb;
    pb[0] = f2bf(b2.x); pb[1] = f2bf(b2.y); pb[2] = f2bf(b2.z); pb[3] = f2bf(b2.w);
    pb[4] = f2bf(b3.x); pb[5] = f2bf(b3.y); pb[6] = f2bf(b3.z); pb[7] = f2bf(b3.w);
    *(short8*)&Bs[srow * 40 + shalf + 8] = pb;
    __syncthreads();
    short8 af[4], bfv[4];
#pragma unroll
    for (int i = 0; i < 4; ++i) af[i] = *(short8*)&As[(wm + i * 16 + fr) * 40 + fq * 8];
#pragma unroll
    for (int j = 0; j < 4; ++j) bfv[j] = *(short8*)&Bs[(wn + j * 16 + fr) * 40 + fq * 8];
#pragma unroll
    for (int i = 0; i < 4; ++i)
#pragma unroll
      for (int j = 0; j < 4; ++j)
        acc[i][j] = __builtin_amdgcn_mfma_f32_16x16x32_bf16(af[i], bfv[j], acc[i][j], 0, 0, 0);
  }
#pragma unroll
  for (int j = 0; j < 4; ++j) {
    int col = n0 + wn + j * 16 + fr;
    float bias = (col < G3) ? bf[col] : bb[col - G3];
#pragma unroll
    for (int i = 0; i < 4; ++i) {
      int rowb = m0 + wm + i * 16 + fq * 4;
#pragma unroll
      for (int rg = 0; rg < 4; ++rg)
        C[(size_t)(rowb + rg) * 384 + col] = acc[i][j][rg] + bias;
    }
  }
}

// ---------------- K2: Bi-GRU, 4 waves per (b,dir) -----------------------------
__global__ __launch_bounds__(256, 1) void gru_kernel(const float* __restrict__ C,
                                                     const float* __restrict__ Whh_f,
                                                     const float* __restrict__ bhh_f,
                                                     const float* __restrict__ Whh_b,
                                                     const float* __restrict__ bhh_b,
                                                     float* __restrict__ out) {
  __shared__ __align__(16) float hbuf[2][64];
  const int wg = blockIdx.x;
  const int rev = (wg >= Bn) ? 1 : 0;
  const int b = wg & (Bn - 1);
  const int tid = threadIdx.x;
  const int w = tid >> 6;
  const int lane = tid & 63;
  const int r = lane >> 2;
  const int kc = lane & 3;
  const int row = 16 * w + r;
  const int k0 = 16 * kc;
  const float* Whh = rev ? Whh_b : Whh_f;
  const float* bhh = rev ? bhh_b : bhh_f;
  const int colBase = rev ? G3 : 0;
  const int dirOff = rev ? Hn : 0;
  float4 wv[3][4];
#pragma unroll
  for (int g = 0; g < 3; ++g)
#pragma unroll
    for (int q = 0; q < 4; ++q) {
      wv[g][q] = *(const float4*)&Whh[(size_t)(g * 64 + row) * 64 + k0 + 4 * q];
      asm volatile("" : "+v"(wv[g][q].x), "+v"(wv[g][q].y), "+v"(wv[g][q].z), "+v"(wv[g][q].w));
    }
  const float brr = bhh[row], bzz = bhh[64 + row], bnn = bhh[128 + row];
  if (tid < 64) { hbuf[0][tid] = 0.f; hbuf[1][tid] = 0.f; }
  float h = 0.f;
  int tt = rev ? (Sn - 1) : 0;
  const int stp = rev ? -1 : 1;
  const float* x0 = C + (size_t)(b * Sn + tt) * 384 + colBase;
  float xr = x0[row], xz = x0[64 + row], xn = x0[128 + row];
  __syncthreads();
  for (int t = 0; t < Sn; ++t) {
    const int p = t & 1;
    float4 ha = *(const float4*)&hbuf[p][k0 + 0];
    float4 hb = *(const float4*)&hbuf[p][k0 + 4];
    float4 hc = *(const float4*)&hbuf[p][k0 + 8];
    float4 hd = *(const float4*)&hbuf[p][k0 + 12];
    float nxr = 0.f, nxz = 0.f, nxn = 0.f;
    if (t + 1 < Sn) {
      const float* xq = C + (size_t)(b * Sn + tt + stp) * 384 + colBase;
      nxr = xq[row]; nxz = xq[64 + row]; nxn = xq[128 + row];
    }
    float dr, dz, dn;
    {
      float4 wa, wbv, wc, wd;
      wa = wv[0][0]; wbv = wv[0][1]; wc = wv[0][2]; wd = wv[0][3];
      dr = (wa.x * ha.x + wa.y * ha.y + wa.z * ha.z + wa.w * ha.w)
         + (wbv.x * hb.x + wbv.y * hb.y + wbv.z * hb.z + wbv.w * hb.w)
         + (wc.x * hc.x + wc.y * hc.y + wc.z * hc.z + wc.w * hc.w)
         + (wd.x * hd.x + wd.y * hd.y + wd.z * hd.z + wd.w * hd.w);
      wa = wv[1][0]; wbv = wv[1][1]; wc = wv[1][2]; wd = wv[1][3];
      dz = (wa.x * ha.x + wa.y * ha.y + wa.z * ha.z + wa.w * ha.w)
         + (wbv.x * hb.x + wbv.y * hb.y + wbv.z * hb.z + wbv.w * hb.w)
         + (wc.x * hc.x + wc.y * hc.y + wc.z * hc.z + wc.w * hc.w)
         + (wd.x * hd.x + wd.y * hd.y + wd.z * hd.z + wd.w * hd.w);
      wa = wv[2][0]; wbv = wv[2][1]; wc = wv[2][2]; wd = wv[2][3];
      dn = (wa.x * ha.x + wa.y * ha.y + wa.z * ha.z + wa.w * ha.w)
         + (wbv.x * hb.x + wbv.y * hb.y + wbv.z * hb.z + wbv.w * hb.w)
         + (wc.x * hc.x + wc.y * hc.y + wc.z * hc.z + wc.w * hc.w)
         + (wd.x * hd.x + wd.y * hd.y + wd.z * hd.z + wd.w * hd.w);
    }
    dr += __shfl_xor(dr, 1); dr += __shfl_xor(dr, 2);
    dz += __shfl_xor(dz, 1); dz += __shfl_xor(dz, 2);
    dn += __shfl_xor(dn, 1); dn += __shfl_xor(dn, 2);
    float rg = sigmoidf_(xr + brr + dr);
    float zg = sigmoidf_(xz + bzz + dz);
    float ng = tanhf_(xn + rg * (bnn + dn));
    h = (1.f - zg) * ng + zg * h;
    if (kc == 0) {
      hbuf[p ^ 1][row] = h;
      out[(size_t)(b * Sn + tt) * (2 * Hn) + dirOff + row] = h;
    }
    __syncthreads();
    tt += stp;
    xr = nxr; xz = nxz; xn = nxn;
  }
}

// ---------------- K3: qkv projection -----------------------------------------
__global__ __launch_bounds__(256) void qkv_kernel(const float* __restrict__ in2,
                                                  const float* __restrict__ Wqkv,
                                                  const float* __restrict__ bqkv,
                                                  float* __restrict__ qb,
                                                  float* __restrict__ kb,
                                                  float* __restrict__ vb) {
  __shared__ float Ws[96 * 32];
  __shared__ float bs[96];
  const int tid = threadIdx.x;
  for (int i = tid; i < 96 * 32; i += 256) Ws[i] = Wqkv[i];
  if (tid < 96) bs[tid] = bqkv[tid];
  __syncthreads();
  const int idx = blockIdx.x * 256 + tid;
  float x[32];
#pragma unroll
  for (int d4 = 0; d4 < 8; ++d4) {
    float4 v = *(const float4*)&in2[(size_t)idx * 32 + d4 * 4];
    x[d4 * 4 + 0] = v.x; x[d4 * 4 + 1] = v.y; x[d4 * 4 + 2] = v.z; x[d4 * 4 + 3] = v.w;
  }
  for (int g = 0; g < 96; ++g) {
    float a = bs[g];
#pragma unroll
    for (int d = 0; d < 32; ++d) a += x[d] * Ws[g * 32 + d];
    float* dst = (g < 32) ? qb : ((g < 64) ? kb : vb);
    dst[(size_t)idx * 32 + (g & 31)] = a;
  }
}

// ---------------- K4a: attention split-K partial (flash-style) ----------------
// Grid 512: b = blk>>3, qhalf = (blk>>2)&1, split = blk&3. 128 keys per split,
// K/V tiles staged in LDS; per-thread online softmax; raw partial out.
__global__ __launch_bounds__(256) void attn_split(const float* __restrict__ qb,
                                                  const float* __restrict__ kb,
                                                  const float* __restrict__ vb,
                                                  float* __restrict__ part) {
  __shared__ __align__(16) float Ks[128 * 32];
  __shared__ __align__(16) float Vs[128 * 32];
  const int tid = threadIdx.x;
  const int blk = blockIdx.x;
  const int b = blk >> 3;
  const int qhalf = (blk >> 2) & 1;
  const int split = blk & 3;
  const int k0 = split * 128;
  // stage K/V tiles: 1024 float4 each, 4 per thread
#pragma unroll
  for (int i = 0; i < 4; ++i) {
    int f = tid + 256 * i;           // float4 index
    int row = f >> 3, col = (f & 7) * 4;
    *(float4*)&Ks[row * 32 + col] = *(const float4*)&kb[(size_t)(b * Sn + k0 + row) * 32 + col];
    *(float4*)&Vs[row * 32 + col] = *(const float4*)&vb[(size_t)(b * Sn + k0 + row) * 32 + col];
  }
  const int q = b * Sn + qhalf * 256 + tid;  // global query idx
  float qv[32];
#pragma unroll
  for (int d4 = 0; d4 < 8; ++d4) {
    float4 v = *(const float4*)&qb[(size_t)q * 32 + d4 * 4];
    qv[d4 * 4 + 0] = v.x; qv[d4 * 4 + 1] = v.y; qv[d4 * 4 + 2] = v.z; qv[d4 * 4 + 3] = v.w;
  }
  __syncthreads();
  const float scale = 0.17677669529663687f;  // 1/sqrt(32)
  float m = -1e30f, lsum = 0.f;
  float acc[32] = {};
  for (int kk = 0; kk < 128; ++kk) {
    const float4* kr = (const float4*)&Ks[kk * 32];
    float s = 0.f;
#pragma unroll
    for (int d4 = 0; d4 < 8; ++d4) {
      float4 kv = kr[d4];
      s += qv[d4 * 4 + 0] * kv.x + qv[d4 * 4 + 1] * kv.y + qv[d4 * 4 + 2] * kv.z + qv[d4 * 4 + 3] * kv.w;
    }
    s *= scale;
    float mn = fmaxf(m, s);
    float e1 = __expf(m - mn);
    float p = __expf(s - mn);
    lsum = lsum * e1 + p;
    const float4* vr = (const float4*)&Vs[kk * 32];
#pragma unroll
    for (int d4 = 0; d4 < 8; ++d4) {
      float4 vv = vr[d4];
      acc[d4 * 4 + 0] = acc[d4 * 4 + 0] * e1 + p * vv.x;
      acc[d4 * 4 + 1] = acc[d4 * 4 + 1] * e1 + p * vv.y;
      acc[d4 * 4 + 2] = acc[d4 * 4 + 2] * e1 + p * vv.z;
      acc[d4 * 4 + 3] = acc[d4 * 4 + 3] * e1 + p * vv.w;
    }
    m = mn;
  }
  float* rec = part + ((size_t)q * 4 + split) * 36;  // 36 floats, 16B-aligned
#pragma unroll
  for (int d4 = 0; d4 < 8; ++d4) {
    float4 o = {acc[d4 * 4 + 0], acc[d4 * 4 + 1], acc[d4 * 4 + 2], acc[d4 * 4 + 3]};
    *(float4*)&rec[d4 * 4] = o;
  }
  rec[32] = m;
  rec[33] = lsum;
}

// ---------------- K4b: combine partials + out_proj ---------------------------
__global__ __launch_bounds__(256) void attn_combine(const float* __restrict__ part,
                                                    const float* __restrict__ Wout,
                                                    const float* __restrict__ bout,
                                                    float* __restrict__ attn) {
  __shared__ float Ws[32 * 32];
  __shared__ float bs[32];
  const int tid = threadIdx.x;
  for (int i = tid; i < 1024; i += 256) Ws[i] = Wout[i];
  if (tid < 32) bs[tid] = bout[tid];
  __syncthreads();
  const int q = blockIdx.x * 256 + tid;
  const float* rec = part + (size_t)q * 4 * 36;
  float m0 = rec[32], m1 = rec[36 + 32], m2 = rec[72 + 32], m3 = rec[108 + 32];
  float M = fmaxf(fmaxf(m0, m1), fmaxf(m2, m3));
  float w0 = __expf(m0 - M), w1 = __expf(m1 - M), w2 = __expf(m2 - M), w3 = __expf(m3 - M);
  float L = rec[33] * w0 + rec[36 + 33] * w1 + rec[72 + 33] * w2 + rec[108 + 33] * w3;
  float inv = 1.f / L;
  float a[32];
#pragma unroll
  for (int d4 = 0; d4 < 8; ++d4) {
    float4 p0 = *(const float4*)&rec[d4 * 4];
    float4 p1 = *(const float4*)&rec[36 + d4 * 4];
    float4 p2 = *(const float4*)&rec[72 + d4 * 4];
    float4 p3 = *(const float4*)&rec[108 + d4 * 4];
    a[d4 * 4 + 0] = (p0.x * w0 + p1.x * w1 + p2.x * w2 + p3.x * w3) * inv;
    a[d4 * 4 + 1] = (p0.y * w0 + p1.y * w1 + p2.y * w2 + p3.y * w3) * inv;
    a[d4 * 4 + 2] = (p0.z * w0 + p1.z * w1 + p2.z * w2 + p3.z * w3) * inv;
    a[d4 * 4 + 3] = (p0.w * w0 + p1.w * w1 + p2.w * w2 + p3.w * w3) * inv;
  }
#pragma unroll
  for (int j = 0; j < 32; ++j) {
    float o = bs[j];
#pragma unroll
    for (int d = 0; d < 32; ++d) o += a[d] * Ws[j * 32 + d];
    attn[(size_t)q * 32 + j] = o;
  }
}

// ---------------- K5: Wcomb = Wdense(128x16) @ Wfuse_top(16x16) --------------
__global__ __launch_bounds__(256) void wcomb_kernel(const float* __restrict__ Wdense,
                                                    const float* __restrict__ Wfuse,
                                                    float* __restrict__ wcomb) {
  int e = blockIdx.x * 256 + threadIdx.x;
  int i = e >> 4, j = e & 15;
  float a = 0.f;
#pragma unroll
  for (int c = 0; c < 16; ++c) a += Wdense[i * 16 + c] * Wfuse[c * 16 + j];
  wcomb[e] = a;
}

// ---------------- K6: emissions ----------------------------------------------
__global__ __launch_bounds__(256) void emis_kernel(const float* __restrict__ lstm,
                                                   const float* __restrict__ attn,
                                                   const float* __restrict__ wcomb,
                                                   const float* __restrict__ Wfuse,
                                                   float* __restrict__ emis) {
  __shared__ float Wc[128 * 16];
  __shared__ float Wf2[32 * 16];
  const int tid = threadIdx.x;
  for (int i = tid; i < 2048; i += 256) Wc[i] = wcomb[i];
  for (int i = tid; i < 512; i += 256) Wf2[i] = Wfuse[16 * 16 + i];
  __syncthreads();
  const int idx = blockIdx.x * 256 + tid;
  float acc[16] = {};
  for (int i = 0; i < 128; i += 4) {
    float4 lv = *(const float4*)&lstm[(size_t)idx * 128 + i];
    float ll[4] = {lv.x, lv.y, lv.z, lv.w};
#pragma unroll
    for (int u = 0; u < 4; ++u)
#pragma unroll
      for (int j = 0; j < 16; ++j) acc[j] += ll[u] * Wc[(i + u) * 16 + j];
  }
  for (int d = 0; d < 32; d += 4) {
    float4 av = *(const float4*)&attn[(size_t)idx * 32 + d];
    float aa[4] = {av.x, av.y, av.z, av.w};
#pragma unroll
    for (int u = 0; u < 4; ++u)
#pragma unroll
      for (int j = 0; j < 16; ++j) acc[j] += aa[u] * Wf2[(d + u) * 16 + j];
  }
#pragma unroll
  for (int j = 0; j < 16; j += 4) {
    float4 o = {acc[j], acc[j + 1], acc[j + 2], acc[j + 3]};
    *(float4*)&emis[(size_t)idx * 16 + j] = o;
  }
}

// ---------------- K7: CRF numerator ------------------------------------------
__global__ __launch_bounds__(64) void numer_kernel(const float* __restrict__ emis,
                                                   const int* __restrict__ tgt,
                                                   const float* __restrict__ cstart,
                                                   const float* __restrict__ cend,
                                                   const float* __restrict__ ctrans,
                                                   float* __restrict__ numer) {
  const int b = blockIdx.x, l = threadIdx.x;
  float ssum = 0.f;
  for (int t = l; t < Sn; t += 64) {
    int tg = tgt[b * Sn + t];
    ssum += emis[(size_t)(b * Sn + t) * Tn + tg];
    if (t + 1 < Sn) {
      int tg2 = tgt[b * Sn + t + 1];
      ssum += ctrans[tg * Tn + tg2];
    }
  }
  if (l == 0) ssum += cstart[tgt[b * Sn]] + cend[tgt[b * Sn + Sn - 1]];
  for (int off = 32; off > 0; off >>= 1) ssum += __shfl_down(ssum, off);
  if (l == 0) numer[b] = ssum;
}

// ---------------- K8: CRF forward (denominator), shfl-only --------------------
__global__ __launch_bounds__(64) void denom_kernel(const float* __restrict__ emis,
                                                   const float* __restrict__ cstart,
                                                   const float* __restrict__ cend,
                                                   const float* __restrict__ ctrans,
                                                   float* __restrict__ denom) {
  const int b = blockIdx.x;
  const int lane = threadIdx.x;
  const int g = lane >> 4;
  const int j = lane & 15;
  const int i0 = 4 * g;
  float tr0 = ctrans[(i0 + 0) * Tn + j];
  float tr1 = ctrans[(i0 + 1) * Tn + j];
  float tr2 = ctrans[(i0 + 2) * Tn + j];
  float tr3 = ctrans[(i0 + 3) * Tn + j];
  float s = cstart[j] + emis[(size_t)(b * Sn) * Tn + j];
  float em = emis[(size_t)(b * Sn + 1) * Tn + j];
  for (int t = 1; t < Sn; ++t) {
    float s0 = __shfl(s, i0 + 0);
    float s1 = __shfl(s, i0 + 1);
    float s2 = __shfl(s, i0 + 2);
    float s3 = __shfl(s, i0 + 3);
    float v0 = s0 + tr0, v1 = s1 + tr1, v2 = s2 + tr2, v3 = s3 + tr3;
    float m = fmaxf(fmaxf(v0, v1), fmaxf(v2, v3));
    m = fmaxf(m, __shfl_xor(m, 16));
    m = fmaxf(m, __shfl_xor(m, 32));
    float e = __expf(v0 - m) + __expf(v1 - m) + __expf(v2 - m) + __expf(v3 - m);
    e += __shfl_xor(e, 16);
    e += __shfl_xor(e, 32);
    float em_cur = em;
    if (t + 1 < Sn) em = emis[(size_t)(b * Sn + t + 1) * Tn + j];
    s = em_cur + m + __logf(e);
  }
  float f = s + cend[j];
  float m = f;
  m = fmaxf(m, __shfl_xor(m, 1));
  m = fmaxf(m, __shfl_xor(m, 2));
  m = fmaxf(m, __shfl_xor(m, 4));
  m = fmaxf(m, __shfl_xor(m, 8));
  float e = __expf(f - m);
  e += __shfl_xor(e, 1);
  e += __shfl_xor(e, 2);
  e += __shfl_xor(e, 4);
  e += __shfl_xor(e, 8);
  if (lane == 0) denom[b] = m + __logf(e);
}

// ---------------- K9: final scalar -------------------------------------------
__global__ __launch_bounds__(64) void final_kernel(const float* __restrict__ numer,
                                                   const float* __restrict__ denom,
                                                   float* __restrict__ out) {
  const int l = threadIdx.x;
  float d = denom[l] - numer[l];
  for (int off = 32; off > 0; off >>= 1) d += __shfl_down(d, off);
  if (l == 0) out[0] = d * (1.f / 64.f);
}

extern "C" void kernel_launch(void* const* d_in, const int* in_sizes, int n_in,
                              void* d_out, int out_size, void* d_ws, size_t ws_size,
                              hipStream_t stream) {
  (void)in_sizes; (void)n_in; (void)out_size; (void)ws_size;
  const float* bert = (const float*)d_in[0];
  const float* in2 = (const float*)d_in[1];
  const int* tgt = (const int*)d_in[2];
  const float* Wih_f = (const float*)d_in[3];
  const float* Whh_f = (const float*)d_in[4];
  const float* bih_f = (const float*)d_in[5];
  const float* bhh_f = (const float*)d_in[6];
  const float* Wih_b = (const float*)d_in[7];
  const float* Whh_b = (const float*)d_in[8];
  const float* bih_b = (const float*)d_in[9];
  const float* bhh_b = (const float*)d_in[10];
  const float* Wdense = (const float*)d_in[11];
  const float* in_proj_w = (const float*)d_in[12];
  const float* in_proj_b = (const float*)d_in[13];
  const float* out_proj_w = (const float*)d_in[14];
  const float* out_proj_b = (const float*)d_in[15];
  const float* Wfuse = (const float*)d_in[16];
  const float* cstart = (const float*)d_in[17];
  const float* cend = (const float*)d_in[18];
  const float* ctrans = (const float*)d_in[19];

  float* ws = (float*)d_ws;
  float* C = ws;                                    // B*S*384 (dead after gru -> reused for attn partials)
  float* lstm = C + (size_t)Bn * Sn * 384;          // B*S*128
  float* qb = lstm + (size_t)Bn * Sn * 2 * Hn;      // B*S*32
  float* kb = qb + (size_t)Bn * Sn * Pn;
  float* vb = kb + (size_t)Bn * Sn * Pn;
  float* attn = vb + (size_t)Bn * Sn * Pn;
  float* emis = attn + (size_t)Bn * Sn * Pn;        // B*S*16
  float* wcomb = emis + (size_t)Bn * Sn * Tn;       // 2048
  float* numer = wcomb + 128 * 16;                  // 64
  float* denom = numer + Bn;                        // 64
  float* part = C;                                  // 32768*4*36 floats (18.9 MB) < C (50 MB)

  dim3 gg(3, Bn * Sn / 128);
  gemm_mfma<<<gg, 256, 0, stream>>>(bert, Wih_f, Wih_b, bih_f, bih_b, C);
  qkv_kernel<<<Bn * Sn / 256, 256, 0, stream>>>(in2, in_proj_w, in_proj_b, qb, kb, vb);
  wcomb_kernel<<<8, 256, 0, stream>>>(Wdense, Wfuse, wcomb);
  gru_kernel<<<2 * Bn, 256, 0, stream>>>(C, Whh_f, bhh_f, Whh_b, bhh_b, lstm);
  attn_split<<<Bn * 8, 256, 0, stream>>>(qb, kb, vb, part);
  attn_combine<<<Bn * Sn / 256, 256, 0, stream>>>(part, out_proj_w, out_proj_b, attn);
  emis_kernel<<<Bn * Sn / 256, 256, 0, stream>>>(lstm, attn, wcomb, Wfuse, emis);
  numer_kernel<<<Bn, 64, 0, stream>>>(emis, tgt, cstart, cend, ctrans, numer);
  denom_kernel<<<Bn, 64, 0, stream>>>(emis, cstart, cend, ctrans, denom);
  final_kernel<<<1, 64, 0, stream>>>(numer, denom, (float*)d_out);
}

// Round 6
// 734.679 us; speedup vs baseline: 1.7615x; 1.0447x over previous
//
#include <hip/hip_runtime.h>

#define Bn 64
#define Sn 512
#define EB 768
#define Hn 64
#define G3 192
#define Tn 16
#define Pn 32

__device__ __forceinline__ float sigmoidf_(float x) { return 1.f / (1.f + __expf(-x)); }
__device__ __forceinline__ float tanhf_(float x) { return 1.f - 2.f / (__expf(2.f * x) + 1.f); }

__device__ __forceinline__ unsigned short f2bf(float x) {
  union { float f; unsigned u; } v; v.f = x;
  unsigned r = v.u + 0x7fff + ((v.u >> 16) & 1);  // RNE
  return (unsigned short)(r >> 16);
}

typedef __attribute__((ext_vector_type(8))) short short8;
typedef __attribute__((ext_vector_type(4))) float f32x4;

// ---------------- K1: C(32768x384) = bert(32768x768) @ [Wf;Wb]^T + bias, bf16 MFMA
__global__ __launch_bounds__(256) void gemm_mfma(const float* __restrict__ A,
                                                 const float* __restrict__ Wf,
                                                 const float* __restrict__ Wb,
                                                 const float* __restrict__ bf,
                                                 const float* __restrict__ bb,
                                                 float* __restrict__ C) {
  __shared__ __align__(16) unsigned short As[128 * 40];
  __shared__ __align__(16) unsigned short Bs[128 * 40];
  const int tid = threadIdx.x;
  const int n0 = blockIdx.x * 128;
  const int m0 = blockIdx.y * 128;
  const int wv = tid >> 6;
  const int lane = tid & 63;
  const int wm = (wv >> 1) * 64, wn = (wv & 1) * 64;
  const int fr = lane & 15, fq = lane >> 4;
  const int srow = tid >> 1;
  const int shalf = (tid & 1) * 16;
  const int bcol = n0 + srow;
  const float* Wrow = (bcol < G3) ? (Wf + (size_t)bcol * EB) : (Wb + (size_t)(bcol - G3) * EB);
  const float* Arow = A + (size_t)(m0 + srow) * EB;
  f32x4 acc[4][4];
#pragma unroll
  for (int i = 0; i < 4; ++i)
#pragma unroll
    for (int j = 0; j < 4; ++j) acc[i][j] = (f32x4){0.f, 0.f, 0.f, 0.f};

  for (int k0 = 0; k0 < EB; k0 += 32) {
    float4 a0 = *(const float4*)&Arow[k0 + shalf + 0];
    float4 a1 = *(const float4*)&Arow[k0 + shalf + 4];
    float4 a2 = *(const float4*)&Arow[k0 + shalf + 8];
    float4 a3 = *(const float4*)&Arow[k0 + shalf + 12];
    float4 b0 = *(const float4*)&Wrow[k0 + shalf + 0];
    float4 b1 = *(const float4*)&Wrow[k0 + shalf + 4];
    float4 b2 = *(const float4*)&Wrow[k0 + shalf + 8];
    float4 b3 = *(const float4*)&Wrow[k0 + shalf + 12];
    __syncthreads();
    short8 pa, pb;
    pa[0] = f2bf(a0.x); pa[1] = f2bf(a0.y); pa[2] = f2bf(a0.z); pa[3] = f2bf(a0.w);
    pa[4] = f2bf(a1.x); pa[5] = f2bf(a1.y); pa[6] = f2bf(a1.z); pa[7] = f2bf(a1.w);
    *(short8*)&As[srow * 40 + shalf] = pa;
    pa[0] = f2bf(a2.x); pa[1] = f2bf(a2.y); pa[2] = f2bf(a2.z); pa[3] = f2bf(a2.w);
    pa[4] = f2bf(a3.x); pa[5] = f2bf(a3.y); pa[6] = f2bf(a3.z); pa[7] = f2bf(a3.w);
    *(short8*)&As[srow * 40 + shalf + 8] = pa;
    pb[0] = f2bf(b0.x); pb[1] = f2bf(b0.y); pb[2] = f2bf(b0.z); pb[3] = f2bf(b0.w);
    pb[4] = f2bf(b1.x); pb[5] = f2bf(b1.y); pb[6] = f2bf(b1.z); pb[7] = f2bf(b1.w);
    *(short8*)&Bs[srow * 40 + shalf] = pb;
    pb[0] = f2bf(b2.x); pb[1] = f2bf(b2.y); pb[2] = f2bf(b2.z); pb[3] = f2bf(b2.w);
    pb[4] = f2bf(b3.x); pb[5] = f2bf(b3.y); pb[6] = f2bf(b3.z); pb[7] = f2bf(b3.w);
    *(short8*)&Bs[srow * 40 + shalf + 8] = pb;
    __syncthreads();
    short8 af[4], bfv[4];
#pragma unroll
    for (int i = 0; i < 4; ++i) af[i] = *(short8*)&As[(wm + i * 16 + fr) * 40 + fq * 8];
#pragma unroll
    for (int j = 0; j < 4; ++j) bfv[j] = *(short8*)&Bs[(wn + j * 16 + fr) * 40 + fq * 8];
#pragma unroll
    for (int i = 0; i < 4; ++i)
#pragma unroll
      for (int j = 0; j < 4; ++j)
        acc[i][j] = __builtin_amdgcn_mfma_f32_16x16x32_bf16(af[i], bfv[j], acc[i][j], 0, 0, 0);
  }
#pragma unroll
  for (int j = 0; j < 4; ++j) {
    int col = n0 + wn + j * 16 + fr;
    float bias = (col < G3) ? bf[col] : bb[col - G3];
#pragma unroll
    for (int i = 0; i < 4; ++i) {
      int rowb = m0 + wm + i * 16 + fq * 4;
#pragma unroll
      for (int rg = 0; rg < 4; ++rg)
        C[(size_t)(rowb + rg) * 384 + col] = acc[i][j][rg] + bias;
    }
  }
}

// ---------------- K2: Bi-GRU, 4 waves per (b,dir), chunked LDS x-staging ------
// Steady-state step touches ONLY LDS -> the compiler's vmcnt(0) drain before
// each s_barrier is free. Global traffic (x in, h out) batched per 32 steps.
__global__ __launch_bounds__(256, 1) void gru_kernel(const float* __restrict__ C,
                                                     const float* __restrict__ Whh_f,
                                                     const float* __restrict__ bhh_f,
                                                     const float* __restrict__ Whh_b,
                                                     const float* __restrict__ bhh_b,
                                                     float* __restrict__ out) {
  __shared__ __align__(16) float xs[32 * 192];   // 24.5 KB x-chunk
  __shared__ __align__(16) float hbuf[2][64];
  __shared__ __align__(16) float obuf[32 * 64];  // 8 KB h-out buffer
  const int wg = blockIdx.x;
  const int rev = (wg >= Bn) ? 1 : 0;
  const int b = wg & (Bn - 1);
  const int tid = threadIdx.x;
  const int w = tid >> 6;
  const int lane = tid & 63;
  const int r = lane >> 2;
  const int kc = lane & 3;
  const int row = 16 * w + r;
  const int k0 = 16 * kc;
  const float* Whh = rev ? Whh_b : Whh_f;
  const float* bhh = rev ? bhh_b : bhh_f;
  const int colBase = rev ? G3 : 0;
  const int dirOff = rev ? Hn : 0;
  float4 wv[3][4];
#pragma unroll
  for (int g = 0; g < 3; ++g)
#pragma unroll
    for (int q = 0; q < 4; ++q) {
      wv[g][q] = *(const float4*)&Whh[(size_t)(g * 64 + row) * 64 + k0 + 4 * q];
      asm volatile("" : "+v"(wv[g][q].x), "+v"(wv[g][q].y), "+v"(wv[g][q].z), "+v"(wv[g][q].w));
    }
  const float brr = bhh[row], bzz = bhh[64 + row], bnn = bhh[128 + row];
  if (tid < 64) { hbuf[0][tid] = 0.f; hbuf[1][tid] = 0.f; }
  float h = 0.f;
  for (int c = 0; c < 16; ++c) {
    const int cstart = c * 32;
    // flush previous chunk's h outputs (reads obuf; visibility via last step's barrier)
    if (c > 0) {
#pragma unroll
      for (int i = 0; i < 2; ++i) {
        int f = tid + 256 * i;
        int s = f >> 4;
        int c4 = (f & 15) << 2;
        int tp = cstart - 32 + s;
        int orow = rev ? (Sn - 1 - tp) : tp;
        *(float4*)&out[(size_t)(b * Sn + orow) * 128 + dirOff + c4] = *(const float4*)&obuf[s * 64 + c4];
      }
    }
    // stage x chunk: 32 steps x 192 cols, 6 float4 per thread
    float4 st[6];
#pragma unroll
    for (int i = 0; i < 6; ++i) {
      int f = tid + 256 * i;
      int s = f / 48;
      int c4 = (f % 48) << 2;
      int t = cstart + s;
      int grow = rev ? (Sn - 1 - t) : t;
      st[i] = *(const float4*)&C[(size_t)(b * Sn + grow) * 384 + colBase + c4];
    }
#pragma unroll
    for (int i = 0; i < 6; ++i) {
      int f = tid + 256 * i;
      int s = f / 48;
      int c4 = (f % 48) << 2;
      *(float4*)&xs[s * 192 + c4] = st[i];
    }
    __syncthreads();
    float xr = xs[row], xz = xs[64 + row], xn = xs[128 + row];
    for (int s = 0; s < 32; ++s) {
      const int t = cstart + s;
      const int p = t & 1;
      float4 ha = *(const float4*)&hbuf[p][k0 + 0];
      float4 hb = *(const float4*)&hbuf[p][k0 + 4];
      float4 hc = *(const float4*)&hbuf[p][k0 + 8];
      float4 hd = *(const float4*)&hbuf[p][k0 + 12];
      float nxr = 0.f, nxz = 0.f, nxn = 0.f;
      if (s + 1 < 32) {
        const float* xq = &xs[(s + 1) * 192];
        nxr = xq[row]; nxz = xq[64 + row]; nxn = xq[128 + row];
      }
      float dr, dz, dn;
      {
        float4 wa, wbv, wc, wd;
        wa = wv[0][0]; wbv = wv[0][1]; wc = wv[0][2]; wd = wv[0][3];
        dr = (wa.x * ha.x + wa.y * ha.y + wa.z * ha.z + wa.w * ha.w)
           + (wbv.x * hb.x + wbv.y * hb.y + wbv.z * hb.z + wbv.w * hb.w)
           + (wc.x * hc.x + wc.y * hc.y + wc.z * hc.z + wc.w * hc.w)
           + (wd.x * hd.x + wd.y * hd.y + wd.z * hd.z + wd.w * hd.w);
        wa = wv[1][0]; wbv = wv[1][1]; wc = wv[1][2]; wd = wv[1][3];
        dz = (wa.x * ha.x + wa.y * ha.y + wa.z * ha.z + wa.w * ha.w)
           + (wbv.x * hb.x + wbv.y * hb.y + wbv.z * hb.z + wbv.w * hb.w)
           + (wc.x * hc.x + wc.y * hc.y + wc.z * hc.z + wc.w * hc.w)
           + (wd.x * hd.x + wd.y * hd.y + wd.z * hd.z + wd.w * hd.w);
        wa = wv[2][0]; wbv = wv[2][1]; wc = wv[2][2]; wd = wv[2][3];
        dn = (wa.x * ha.x + wa.y * ha.y + wa.z * ha.z + wa.w * ha.w)
           + (wbv.x * hb.x + wbv.y * hb.y + wbv.z * hb.z + wbv.w * hb.w)
           + (wc.x * hc.x + wc.y * hc.y + wc.z * hc.z + wc.w * hc.w)
           + (wd.x * hd.x + wd.y * hd.y + wd.z * hd.z + wd.w * hd.w);
      }
      dr += __shfl_xor(dr, 1); dr += __shfl_xor(dr, 2);
      dz += __shfl_xor(dz, 1); dz += __shfl_xor(dz, 2);
      dn += __shfl_xor(dn, 1); dn += __shfl_xor(dn, 2);
      float rg = sigmoidf_(xr + brr + dr);
      float zg = sigmoidf_(xz + bzz + dz);
      float ng = tanhf_(xn + rg * (bnn + dn));
      h = (1.f - zg) * ng + zg * h;
      if (kc == 0) {
        hbuf[p ^ 1][row] = h;
        obuf[s * 64 + row] = h;
      }
      __syncthreads();
      xr = nxr; xz = nxz; xn = nxn;
    }
  }
  // final flush (last chunk)
#pragma unroll
  for (int i = 0; i < 2; ++i) {
    int f = tid + 256 * i;
    int s = f >> 4;
    int c4 = (f & 15) << 2;
    int tp = Sn - 32 + s;
    int orow = rev ? (Sn - 1 - tp) : tp;
    *(float4*)&out[(size_t)(b * Sn + orow) * 128 + dirOff + c4] = *(const float4*)&obuf[s * 64 + c4];
  }
}

// ---------------- K3: qkv projection -----------------------------------------
__global__ __launch_bounds__(256) void qkv_kernel(const float* __restrict__ in2,
                                                  const float* __restrict__ Wqkv,
                                                  const float* __restrict__ bqkv,
                                                  float* __restrict__ qb,
                                                  float* __restrict__ kb,
                                                  float* __restrict__ vb) {
  __shared__ float Ws[96 * 32];
  __shared__ float bs[96];
  const int tid = threadIdx.x;
  for (int i = tid; i < 96 * 32; i += 256) Ws[i] = Wqkv[i];
  if (tid < 96) bs[tid] = bqkv[tid];
  __syncthreads();
  const int idx = blockIdx.x * 256 + tid;
  float x[32];
#pragma unroll
  for (int d4 = 0; d4 < 8; ++d4) {
    float4 v = *(const float4*)&in2[(size_t)idx * 32 + d4 * 4];
    x[d4 * 4 + 0] = v.x; x[d4 * 4 + 1] = v.y; x[d4 * 4 + 2] = v.z; x[d4 * 4 + 3] = v.w;
  }
  for (int g = 0; g < 96; ++g) {
    float a = bs[g];
#pragma unroll
    for (int d = 0; d < 32; ++d) a += x[d] * Ws[g * 32 + d];
    float* dst = (g < 32) ? qb : ((g < 64) ? kb : vb);
    dst[(size_t)idx * 32 + (g & 31)] = a;
  }
}

// ---------------- K4a: attention split-K partial (flash-style) ----------------
__global__ __launch_bounds__(256) void attn_split(const float* __restrict__ qb,
                                                  const float* __restrict__ kb,
                                                  const float* __restrict__ vb,
                                                  float* __restrict__ part) {
  __shared__ __align__(16) float Ks[128 * 32];
  __shared__ __align__(16) float Vs[128 * 32];
  const int tid = threadIdx.x;
  const int blk = blockIdx.x;
  const int b = blk >> 3;
  const int qhalf = (blk >> 2) & 1;
  const int split = blk & 3;
  const int k0 = split * 128;
#pragma unroll
  for (int i = 0; i < 4; ++i) {
    int f = tid + 256 * i;
    int row = f >> 3, col = (f & 7) * 4;
    *(float4*)&Ks[row * 32 + col] = *(const float4*)&kb[(size_t)(b * Sn + k0 + row) * 32 + col];
    *(float4*)&Vs[row * 32 + col] = *(const float4*)&vb[(size_t)(b * Sn + k0 + row) * 32 + col];
  }
  const int q = b * Sn + qhalf * 256 + tid;
  float qv[32];
#pragma unroll
  for (int d4 = 0; d4 < 8; ++d4) {
    float4 v = *(const float4*)&qb[(size_t)q * 32 + d4 * 4];
    qv[d4 * 4 + 0] = v.x; qv[d4 * 4 + 1] = v.y; qv[d4 * 4 + 2] = v.z; qv[d4 * 4 + 3] = v.w;
  }
  __syncthreads();
  const float scale = 0.17677669529663687f;
  float m = -1e30f, lsum = 0.f;
  float acc[32] = {};
  for (int kk = 0; kk < 128; ++kk) {
    const float4* kr = (const float4*)&Ks[kk * 32];
    float s = 0.f;
#pragma unroll
    for (int d4 = 0; d4 < 8; ++d4) {
      float4 kv = kr[d4];
      s += qv[d4 * 4 + 0] * kv.x + qv[d4 * 4 + 1] * kv.y + qv[d4 * 4 + 2] * kv.z + qv[d4 * 4 + 3] * kv.w;
    }
    s *= scale;
    float mn = fmaxf(m, s);
    float e1 = __expf(m - mn);
    float p = __expf(s - mn);
    lsum = lsum * e1 + p;
    const float4* vr = (const float4*)&Vs[kk * 32];
#pragma unroll
    for (int d4 = 0; d4 < 8; ++d4) {
      float4 vv = vr[d4];
      acc[d4 * 4 + 0] = acc[d4 * 4 + 0] * e1 + p * vv.x;
      acc[d4 * 4 + 1] = acc[d4 * 4 + 1] * e1 + p * vv.y;
      acc[d4 * 4 + 2] = acc[d4 * 4 + 2] * e1 + p * vv.z;
      acc[d4 * 4 + 3] = acc[d4 * 4 + 3] * e1 + p * vv.w;
    }
    m = mn;
  }
  float* rec = part + ((size_t)q * 4 + split) * 36;
#pragma unroll
  for (int d4 = 0; d4 < 8; ++d4) {
    float4 o = {acc[d4 * 4 + 0], acc[d4 * 4 + 1], acc[d4 * 4 + 2], acc[d4 * 4 + 3]};
    *(float4*)&rec[d4 * 4] = o;
  }
  rec[32] = m;
  rec[33] = lsum;
}

// ---------------- K4b: combine partials + out_proj ---------------------------
__global__ __launch_bounds__(256) void attn_combine(const float* __restrict__ part,
                                                    const float* __restrict__ Wout,
                                                    const float* __restrict__ bout,
                                                    float* __restrict__ attn) {
  __shared__ float Ws[32 * 32];
  __shared__ float bs[32];
  const int tid = threadIdx.x;
  for (int i = tid; i < 1024; i += 256) Ws[i] = Wout[i];
  if (tid < 32) bs[tid] = bout[tid];
  __syncthreads();
  const int q = blockIdx.x * 256 + tid;
  const float* rec = part + (size_t)q * 4 * 36;
  float m0 = rec[32], m1 = rec[36 + 32], m2 = rec[72 + 32], m3 = rec[108 + 32];
  float M = fmaxf(fmaxf(m0, m1), fmaxf(m2, m3));
  float w0 = __expf(m0 - M), w1 = __expf(m1 - M), w2 = __expf(m2 - M), w3 = __expf(m3 - M);
  float L = rec[33] * w0 + rec[36 + 33] * w1 + rec[72 + 33] * w2 + rec[108 + 33] * w3;
  float inv = 1.f / L;
  float a[32];
#pragma unroll
  for (int d4 = 0; d4 < 8; ++d4) {
    float4 p0 = *(const float4*)&rec[d4 * 4];
    float4 p1 = *(const float4*)&rec[36 + d4 * 4];
    float4 p2 = *(const float4*)&rec[72 + d4 * 4];
    float4 p3 = *(const float4*)&rec[108 + d4 * 4];
    a[d4 * 4 + 0] = (p0.x * w0 + p1.x * w1 + p2.x * w2 + p3.x * w3) * inv;
    a[d4 * 4 + 1] = (p0.y * w0 + p1.y * w1 + p2.y * w2 + p3.y * w3) * inv;
    a[d4 * 4 + 2] = (p0.z * w0 + p1.z * w1 + p2.z * w2 + p3.z * w3) * inv;
    a[d4 * 4 + 3] = (p0.w * w0 + p1.w * w1 + p2.w * w2 + p3.w * w3) * inv;
  }
#pragma unroll
  for (int j = 0; j < 32; ++j) {
    float o = bs[j];
#pragma unroll
    for (int d = 0; d < 32; ++d) o += a[d] * Ws[j * 32 + d];
    attn[(size_t)q * 32 + j] = o;
  }
}

// ---------------- K5: Wcomb = Wdense(128x16) @ Wfuse_top(16x16) --------------
__global__ __launch_bounds__(256) void wcomb_kernel(const float* __restrict__ Wdense,
                                                    const float* __restrict__ Wfuse,
                                                    float* __restrict__ wcomb) {
  int e = blockIdx.x * 256 + threadIdx.x;
  int i = e >> 4, j = e & 15;
  float a = 0.f;
#pragma unroll
  for (int c = 0; c < 16; ++c) a += Wdense[i * 16 + c] * Wfuse[c * 16 + j];
  wcomb[e] = a;
}

// ---------------- K6: emissions ----------------------------------------------
__global__ __launch_bounds__(256) void emis_kernel(const float* __restrict__ lstm,
                                                   const float* __restrict__ attn,
                                                   const float* __restrict__ wcomb,
                                                   const float* __restrict__ Wfuse,
                                                   float* __restrict__ emis) {
  __shared__ float Wc[128 * 16];
  __shared__ float Wf2[32 * 16];
  const int tid = threadIdx.x;
  for (int i = tid; i < 2048; i += 256) Wc[i] = wcomb[i];
  for (int i = tid; i < 512; i += 256) Wf2[i] = Wfuse[16 * 16 + i];
  __syncthreads();
  const int idx = blockIdx.x * 256 + tid;
  float acc[16] = {};
  for (int i = 0; i < 128; i += 4) {
    float4 lv = *(const float4*)&lstm[(size_t)idx * 128 + i];
    float ll[4] = {lv.x, lv.y, lv.z, lv.w};
#pragma unroll
    for (int u = 0; u < 4; ++u)
#pragma unroll
      for (int j = 0; j < 16; ++j) acc[j] += ll[u] * Wc[(i + u) * 16 + j];
  }
  for (int d = 0; d < 32; d += 4) {
    float4 av = *(const float4*)&attn[(size_t)idx * 32 + d];
    float aa[4] = {av.x, av.y, av.z, av.w};
#pragma unroll
    for (int u = 0; u < 4; ++u)
#pragma unroll
      for (int j = 0; j < 16; ++j) acc[j] += aa[u] * Wf2[(d + u) * 16 + j];
  }
#pragma unroll
  for (int j = 0; j < 16; j += 4) {
    float4 o = {acc[j], acc[j + 1], acc[j + 2], acc[j + 3]};
    *(float4*)&emis[(size_t)idx * 16 + j] = o;
  }
}

// ---------------- K7: CRF numerator ------------------------------------------
__global__ __launch_bounds__(64) void numer_kernel(const float* __restrict__ emis,
                                                   const int* __restrict__ tgt,
                                                   const float* __restrict__ cstart,
                                                   const float* __restrict__ cend,
                                                   const float* __restrict__ ctrans,
                                                   float* __restrict__ numer) {
  const int b = blockIdx.x, l = threadIdx.x;
  float ssum = 0.f;
  for (int t = l; t < Sn; t += 64) {
    int tg = tgt[b * Sn + t];
    ssum += emis[(size_t)(b * Sn + t) * Tn + tg];
    if (t + 1 < Sn) {
      int tg2 = tgt[b * Sn + t + 1];
      ssum += ctrans[tg * Tn + tg2];
    }
  }
  if (l == 0) ssum += cstart[tgt[b * Sn]] + cend[tgt[b * Sn + Sn - 1]];
  for (int off = 32; off > 0; off >>= 1) ssum += __shfl_down(ssum, off);
  if (l == 0) numer[b] = ssum;
}

// ---------------- K8: CRF forward (denominator), shfl-only --------------------
__global__ __launch_bounds__(64) void denom_kernel(const float* __restrict__ emis,
                                                   const float* __restrict__ cstart,
                                                   const float* __restrict__ cend,
                                                   const float* __restrict__ ctrans,
                                                   float* __restrict__ denom) {
  const int b = blockIdx.x;
  const int lane = threadIdx.x;
  const int g = lane >> 4;
  const int j = lane & 15;
  const int i0 = 4 * g;
  float tr0 = ctrans[(i0 + 0) * Tn + j];
  float tr1 = ctrans[(i0 + 1) * Tn + j];
  float tr2 = ctrans[(i0 + 2) * Tn + j];
  float tr3 = ctrans[(i0 + 3) * Tn + j];
  float s = cstart[j] + emis[(size_t)(b * Sn) * Tn + j];
  float em = emis[(size_t)(b * Sn + 1) * Tn + j];
  for (int t = 1; t < Sn; ++t) {
    float s0 = __shfl(s, i0 + 0);
    float s1 = __shfl(s, i0 + 1);
    float s2 = __shfl(s, i0 + 2);
    float s3 = __shfl(s, i0 + 3);
    float v0 = s0 + tr0, v1 = s1 + tr1, v2 = s2 + tr2, v3 = s3 + tr3;
    float m = fmaxf(fmaxf(v0, v1), fmaxf(v2, v3));
    m = fmaxf(m, __shfl_xor(m, 16));
    m = fmaxf(m, __shfl_xor(m, 32));
    float e = __expf(v0 - m) + __expf(v1 - m) + __expf(v2 - m) + __expf(v3 - m);
    e += __shfl_xor(e, 16);
    e += __shfl_xor(e, 32);
    float em_cur = em;
    if (t + 1 < Sn) em = emis[(size_t)(b * Sn + t + 1) * Tn + j];
    s = em_cur + m + __logf(e);
  }
  float f = s + cend[j];
  float m = f;
  m = fmaxf(m, __shfl_xor(m, 1));
  m = fmaxf(m, __shfl_xor(m, 2));
  m = fmaxf(m, __shfl_xor(m, 4));
  m = fmaxf(m, __shfl_xor(m, 8));
  float e = __expf(f - m);
  e += __shfl_xor(e, 1);
  e += __shfl_xor(e, 2);
  e += __shfl_xor(e, 4);
  e += __shfl_xor(e, 8);
  if (lane == 0) denom[b] = m + __logf(e);
}

// ---------------- K9: final scalar -------------------------------------------
__global__ __launch_bounds__(64) void final_kernel(const float* __restrict__ numer,
                                                   const float* __restrict__ denom,
                                                   float* __restrict__ out) {
  const int l = threadIdx.x;
  float d = denom[l] - numer[l];
  for (int off = 32; off > 0; off >>= 1) d += __shfl_down(d, off);
  if (l == 0) out[0] = d * (1.f / 64.f);
}

extern "C" void kernel_launch(void* const* d_in, const int* in_sizes, int n_in,
                              void* d_out, int out_size, void* d_ws, size_t ws_size,
                              hipStream_t stream) {
  (void)in_sizes; (void)n_in; (void)out_size; (void)ws_size;
  const float* bert = (const float*)d_in[0];
  const float* in2 = (const float*)d_in[1];
  const int* tgt = (const int*)d_in[2];
  const float* Wih_f = (const float*)d_in[3];
  const float* Whh_f = (const float*)d_in[4];
  const float* bih_f = (const float*)d_in[5];
  const float* bhh_f = (const float*)d_in[6];
  const float* Wih_b = (const float*)d_in[7];
  const float* Whh_b = (const float*)d_in[8];
  const float* bih_b = (const float*)d_in[9];
  const float* bhh_b = (const float*)d_in[10];
  const float* Wdense = (const float*)d_in[11];
  const float* in_proj_w = (const float*)d_in[12];
  const float* in_proj_b = (const float*)d_in[13];
  const float* out_proj_w = (const float*)d_in[14];
  const float* out_proj_b = (const float*)d_in[15];
  const float* Wfuse = (const float*)d_in[16];
  const float* cstart = (const float*)d_in[17];
  const float* cend = (const float*)d_in[18];
  const float* ctrans = (const float*)d_in[19];

  float* ws = (float*)d_ws;
  float* C = ws;                                    // B*S*384 (dead after gru -> reused for attn partials)
  float* lstm = C + (size_t)Bn * Sn * 384;          // B*S*128
  float* qb = lstm + (size_t)Bn * Sn * 2 * Hn;      // B*S*32
  float* kb = qb + (size_t)Bn * Sn * Pn;
  float* vb = kb + (size_t)Bn * Sn * Pn;
  float* attn = vb + (size_t)Bn * Sn * Pn;
  float* emis = attn + (size_t)Bn * Sn * Pn;        // B*S*16
  float* wcomb = emis + (size_t)Bn * Sn * Tn;       // 2048
  float* numer = wcomb + 128 * 16;                  // 64
  float* denom = numer + Bn;                        // 64
  float* part = C;                                  // 32768*4*36 floats (18.9 MB) < C (50 MB)

  dim3 gg(3, Bn * Sn / 128);
  gemm_mfma<<<gg, 256, 0, stream>>>(bert, Wih_f, Wih_b, bih_f, bih_b, C);
  qkv_kernel<<<Bn * Sn / 256, 256, 0, stream>>>(in2, in_proj_w, in_proj_b, qb, kb, vb);
  wcomb_kernel<<<8, 256, 0, stream>>>(Wdense, Wfuse, wcomb);
  gru_kernel<<<2 * Bn, 256, 0, stream>>>(C, Whh_f, bhh_f, Whh_b, bhh_b, lstm);
  attn_split<<<Bn * 8, 256, 0, stream>>>(qb, kb, vb, part);
  attn_combine<<<Bn * Sn / 256, 256, 0, stream>>>(part, out_proj_w, out_proj_b, attn);
  emis_kernel<<<Bn * Sn / 256, 256, 0, stream>>>(lstm, attn, wcomb, Wfuse, emis);
  numer_kernel<<<Bn, 64, 0, stream>>>(emis, tgt, cstart, cend, ctrans, numer);
  denom_kernel<<<Bn, 64, 0, stream>>>(emis, cstart, cend, ctrans, denom);
  final_kernel<<<1, 64, 0, stream>>>(numer, denom, (float*)d_out);
}